// Round 16
// baseline (2357.476 us; speedup 1.0000x reference)
//
#include <hip/hip_runtime.h>
#include <math.h>

#define NN 1024           // N (logical)
#define NB 64             // panel width
#define TB 128            // tail handled by tailsyrk+finish
#define CROSS (NN - TB)   // 896: panel loop covers p < CROSS
#define NSAMP 64          // n_mc
// r25: banded-packed cov. Band b (rows 64b..64b+63) stores cols 0..64(b+1)+15
// (stride bs(b)=64b+80). Per-sample 573440 floats -> 64 samples = 147MB,
// ONE L3-resident batch.
#define SMPL 573440
#define TSQN (TB*TB)      // dense tail square per sample (finish input)

#define CCONST  (-0.91893853320467274f)   // -0.5*log(2*pi)
#define LOG2PI  (1.8378770664093453f)

__device__ __forceinline__ int rowoff(int i) {
    int b = i >> 6;
    return (2048*b + 3072)*b + (i & 63)*(64*b + 80);
}
__device__ __forceinline__ float bcastf(float v, int lane) {
    return __int_as_float(__builtin_amdgcn_readlane(__float_as_int(v), lane));
}
__device__ __forceinline__ float softplus_d(float v) {
    return (v > 20.f ? v : log1pf(expf(v))) + 1e-7f;
}
__device__ __forceinline__ float log_normal_f(float v, float mean, float s, float eps) {
    float d = v - mean;
    return -d * d / (2.f * s * s + eps) - logf(s) + CCONST;
}
__device__ __forceinline__ float log_lognormal_f(float v, float mean, float s) {
    float lv = logf(v);
    float d = lv - mean;
    return -d * d / (2.f * s * s + 1e-6f) - lv - logf(s) + CCONST;
}
__device__ __forceinline__ void fma4(float4& c, float a, const float4& b) {
    c.x = fmaf(a, b.x, c.x); c.y = fmaf(a, b.y, c.y);
    c.z = fmaf(a, b.z, c.z); c.w = fmaf(a, b.w, c.w);
}

// ---------------- per-sample scalars ----------------
__global__ void scal_kernel(const float* __restrict__ z,
    const float* qbm, const float* qbs, const float* qsm, const float* qss,
    const float* qem, const float* qes, const float* qzm, const float* qzs,
    const float* qnm, const float* qns, float* __restrict__ scal)
{
    int m = threadIdx.x;
    if (m >= NSAMP) return;
    float z0 = z[m*5+0], z1 = z[m*5+1], z2 = z[m*5+2], z3 = z[m*5+3], z4 = z[m*5+4];
    float spb = softplus_d(qbs[0]);
    float sps = softplus_d(qss[0]);
    float spe = softplus_d(qes[0]);
    float spz = softplus_d(qzs[0]);
    float spn = softplus_d(qns[0]);
    float sigma2 = expf(z0 * sps + qsm[0]);
    float beta   = z1 * spb + qbm[0];
    float eta    = expf(z2 * spe + qem[0]);
    float lsZ    = expf(z3 * spz + qzm[0]);
    float lsN    = expf(z4 * spn + qnm[0]);
    float s0 = softplus_d(sqrtf(logf(2.f)));
    float lp = log_normal_f(beta, 0.f, 1.f, 1e-5f)
             + log_lognormal_f(sigma2, 1.f, s0)
             + log_lognormal_f(eta,    1.f, s0)
             + log_lognormal_f(lsZ,    1.f, s0)
             + log_lognormal_f(lsN,    1.f, s0);
    float lq = log_normal_f(beta, qbm[0], spb, 1e-5f)
             + log_lognormal_f(sigma2, qsm[0], sps)
             + log_lognormal_f(eta,    qem[0], spe)
             + log_lognormal_f(lsZ,    qzm[0], spz)
             + log_lognormal_f(lsN,    qnm[0], spn);
    scal[m]           = sigma2;
    scal[NSAMP + m]   = eta;
    scal[2*NSAMP + m] = 1.f / lsZ;
    scal[3*NSAMP + m] = 1.f / lsN;
    scal[4*NSAMP + m] = beta;
    scal[5*NSAMP + m] = lp - lq;
}

// ---------------- slim covariance build + bvec/stats init ----------------
// r27: 1D grid, ml = bid % mc -> sample ml's writes land on XCD ml%8's L2
// (matches the panel kernels' read mapping).
__global__ __launch_bounds__(256)
void covslim_kernel(float* __restrict__ cov, float* __restrict__ tsq,
                    const float* __restrict__ scal,
                    const float* __restrict__ x, const float* __restrict__ y,
                    float* __restrict__ bvec, float* __restrict__ stats,
                    int mbase, int mc)
{
    int bid = blockIdx.x;
    int ml  = bid % mc;
    int bx  = bid / mc;                        // 0..79
    int m  = mbase + ml;
    float sigma2 = scal[m];
    float eta    = scal[NSAMP + m];
    float ilZ    = scal[2*NSAMP + m];
    float ilN    = scal[3*NSAMP + m];
    float* C = cov + (size_t)ml * SMPL;
    int tid = threadIdx.x;

    if (bx == 0 && tid == 0) { stats[2*m] = 0.f; stats[2*m+1] = 0.f; }

    if (bx < 64) {
        // stripe: 16 rows x 64 cols per block (lower triangle only)
        int i  = bx * 16 + (tid >> 4);
        int j0 = (tid & 15) * 4;
        if ((tid & 15) == 0) bvec[(size_t)m * NN + i] = y[i] - scal[4*NSAMP + m];
        if (j0 > i) return;
        float xi0 = x[2*i]   * ilZ;
        float xi1 = x[2*i+1] * ilN;
        float4 xa = *(const float4*)(x + 2*j0);
        float4 xb = *(const float4*)(x + 2*j0 + 4);
        float v[4]; float d0, d1;
        d0 = xa.x*ilZ - xi0; d1 = xa.y*ilN - xi1; v[0] = eta*__expf(-0.5f*(d0*d0+d1*d1));
        d0 = xa.z*ilZ - xi0; d1 = xa.w*ilN - xi1; v[1] = eta*__expf(-0.5f*(d0*d0+d1*d1));
        d0 = xb.x*ilZ - xi0; d1 = xb.y*ilN - xi1; v[2] = eta*__expf(-0.5f*(d0*d0+d1*d1));
        d0 = xb.z*ilZ - xi0; d1 = xb.w*ilN - xi1; v[3] = eta*__expf(-0.5f*(d0*d0+d1*d1));
        #pragma unroll
        for (int q = 0; q < 4; ++q) if (j0 + q == i) v[q] += sigma2;
        float* row = C + rowoff(i);
        if (j0 + 3 <= i) {
            float4 o; o.x = v[0]; o.y = v[1]; o.z = v[2]; o.w = v[3];
            *(float4*)(row + j0) = o;
        } else {
            #pragma unroll
            for (int q = 0; q < 4; ++q) if (j0 + q <= i) row[j0+q] = v[q];
        }
    } else {
        // tail: 8 rows x 128 cols per block -> dense tsq[128][128]
        int bx2 = bx - 64;                         // 0..15
        int tr  = bx2 * 8 + (tid >> 5);            // 0..127 tail-local row
        int tc  = (tid & 31) * 4;                  // 0..124 tail-local col
        int i   = CROSS + tr;
        int j0  = CROSS + tc;
        float xi0 = x[2*i]   * ilZ;
        float xi1 = x[2*i+1] * ilN;
        float4 xa = *(const float4*)(x + 2*j0);
        float4 xb = *(const float4*)(x + 2*j0 + 4);
        float v[4]; float d0, d1;
        d0 = xa.x*ilZ - xi0; d1 = xa.y*ilN - xi1; v[0] = eta*__expf(-0.5f*(d0*d0+d1*d1));
        d0 = xa.z*ilZ - xi0; d1 = xa.w*ilN - xi1; v[1] = eta*__expf(-0.5f*(d0*d0+d1*d1));
        d0 = xb.x*ilZ - xi0; d1 = xb.y*ilN - xi1; v[2] = eta*__expf(-0.5f*(d0*d0+d1*d1));
        d0 = xb.z*ilZ - xi0; d1 = xb.w*ilN - xi1; v[3] = eta*__expf(-0.5f*(d0*d0+d1*d1));
        #pragma unroll
        for (int q = 0; q < 4; ++q) if (j0 + q == i) v[q] += sigma2;
        float4 o; o.x = v[0]; o.y = v[1]; o.z = v[2]; o.w = v[3];
        *(float4*)(tsq + (size_t)ml * TSQN + tr * TB + tc) = o;
    }
}

// ---------------- left-looking block-column update (GEMM, K = p) ----------------
// r26: software-pipelined staging (works now that the set is L3-resident).
__global__ __launch_bounds__(256)
void update_kernel(float* __restrict__ covb, const float* __restrict__ scal,
                   const float* __restrict__ x, int mbase, int p, int mc)
{
    int bid = blockIdx.x;
    int ml  = bid % mc;
    int bx  = bid / mc;
    int m  = mbase + ml;
    float* C = covb + (size_t)ml * SMPL;
    int rowbase = p + bx * 128;
    int bofp = rowoff(p);
    int bsp  = 64*(p>>6) + 80;

    __shared__ __align__(16) float As[32][132];  // k-major, 128 rows
    __shared__ __align__(16) float Bs[32][68];   // k-major, 64 rows

    int tid = threadIdx.x;
    int tx = tid & 7,  ty = tid >> 3;
    int c0 = tx * 8,   r0 = ty * 4;

    float4 acc[4][2];
    #pragma unroll
    for (int r = 0; r < 4; ++r) { acc[r][0] = make_float4(0,0,0,0); acc[r][1] = make_float4(0,0,0,0); }

    // prefetch k-step 0 into registers
    float4 ra[4], rb[2];
    #pragma unroll
    for (int t = 0; t < 4; ++t) {
        int idx = tid + t * 256;
        int ii = idx >> 3, c4 = (idx & 7) << 2;
        int gr = rowbase + ii;
        ra[t] = make_float4(0,0,0,0);
        if (gr < NN) ra[t] = *(const float4*)(C + rowoff(gr) + c4);
    }
    #pragma unroll
    for (int t = 0; t < 2; ++t) {
        int idx = tid + t * 256;
        int ii = idx >> 3, c4 = (idx & 7) << 2;
        rb[t] = *(const float4*)(C + bofp + ii * bsp + c4);
    }

    for (int ks = 0; ks < p; ks += 32) {
        #pragma unroll
        for (int t = 0; t < 4; ++t) {
            int idx = tid + t * 256;
            int ii = idx >> 3, c4 = (idx & 7) << 2;
            As[c4+0][ii] = ra[t].x; As[c4+1][ii] = ra[t].y;
            As[c4+2][ii] = ra[t].z; As[c4+3][ii] = ra[t].w;
        }
        #pragma unroll
        for (int t = 0; t < 2; ++t) {
            int idx = tid + t * 256;
            int ii = idx >> 3, c4 = (idx & 7) << 2;
            Bs[c4+0][ii] = rb[t].x; Bs[c4+1][ii] = rb[t].y;
            Bs[c4+2][ii] = rb[t].z; Bs[c4+3][ii] = rb[t].w;
        }
        __syncthreads();
        int kn = ks + 32;
        if (kn < p) {
            #pragma unroll
            for (int t = 0; t < 4; ++t) {
                int idx = tid + t * 256;
                int ii = idx >> 3, c4 = (idx & 7) << 2;
                int gr = rowbase + ii;
                ra[t] = make_float4(0,0,0,0);
                if (gr < NN) ra[t] = *(const float4*)(C + rowoff(gr) + kn + c4);
            }
            #pragma unroll
            for (int t = 0; t < 2; ++t) {
                int idx = tid + t * 256;
                int ii = idx >> 3, c4 = (idx & 7) << 2;
                rb[t] = *(const float4*)(C + bofp + ii * bsp + kn + c4);
            }
        }
        #pragma unroll
        for (int k = 0; k < 32; ++k) {
            float4 b0 = *(const float4*)&Bs[k][c0];
            float4 b1 = *(const float4*)&Bs[k][c0 + 4];
            float4 a0 = *(const float4*)&As[k][r0];
            float ar[4] = {a0.x, a0.y, a0.z, a0.w};
            #pragma unroll
            for (int r = 0; r < 4; ++r) {
                fma4(acc[r][0], ar[r], b0);
                fma4(acc[r][1], ar[r], b1);
            }
        }
        __syncthreads();
    }

    int jcol = p + c0;
    float sigma2 = scal[m];
    float eta    = scal[NSAMP + m];
    float ilZ    = scal[2*NSAMP + m];
    float ilN    = scal[3*NSAMP + m];
    float4 xa0 = *(const float4*)(x + 2*jcol);
    float4 xb0 = *(const float4*)(x + 2*jcol + 4);
    float4 xa1 = *(const float4*)(x + 2*jcol + 8);
    float4 xb1 = *(const float4*)(x + 2*jcol + 12);
    #pragma unroll
    for (int r = 0; r < 4; ++r) {
        int g = rowbase + r0 + r;
        if (g < NN) {
            float xi0 = x[2*g]   * ilZ;
            float xi1 = x[2*g+1] * ilN;
            float v[8]; float d0, d1;
            d0 = xa0.x*ilZ - xi0; d1 = xa0.y*ilN - xi1; v[0] = eta*__expf(-0.5f*(d0*d0+d1*d1));
            d0 = xa0.z*ilZ - xi0; d1 = xa0.w*ilN - xi1; v[1] = eta*__expf(-0.5f*(d0*d0+d1*d1));
            d0 = xb0.x*ilZ - xi0; d1 = xb0.y*ilN - xi1; v[2] = eta*__expf(-0.5f*(d0*d0+d1*d1));
            d0 = xb0.z*ilZ - xi0; d1 = xb0.w*ilN - xi1; v[3] = eta*__expf(-0.5f*(d0*d0+d1*d1));
            d0 = xa1.x*ilZ - xi0; d1 = xa1.y*ilN - xi1; v[4] = eta*__expf(-0.5f*(d0*d0+d1*d1));
            d0 = xa1.z*ilZ - xi0; d1 = xa1.w*ilN - xi1; v[5] = eta*__expf(-0.5f*(d0*d0+d1*d1));
            d0 = xb1.x*ilZ - xi0; d1 = xb1.y*ilN - xi1; v[6] = eta*__expf(-0.5f*(d0*d0+d1*d1));
            d0 = xb1.z*ilZ - xi0; d1 = xb1.w*ilN - xi1; v[7] = eta*__expf(-0.5f*(d0*d0+d1*d1));
            #pragma unroll
            for (int qq = 0; qq < 8; ++qq) if (jcol + qq == g) v[qq] += sigma2;
            float* cp = C + rowoff(g) + jcol;
            float4 u0, u1;
            u0.x = v[0] - acc[r][0].x; u0.y = v[1] - acc[r][0].y;
            u0.z = v[2] - acc[r][0].z; u0.w = v[3] - acc[r][0].w;
            u1.x = v[4] - acc[r][1].x; u1.y = v[5] - acc[r][1].y;
            u1.z = v[6] - acc[r][1].z; u1.w = v[7] - acc[r][1].w;
            *(float4*)cp = u0;
            *((float4*)cp + 1) = u1;
        }
    }
}

// ---------------- small-tile update for late panels ----------------
__global__ __launch_bounds__(256)
void update_small_kernel(float* __restrict__ covb, const float* __restrict__ scal,
                         const float* __restrict__ x, int mbase, int p, int mc, int nbx)
{
    int bid  = blockIdx.x;
    int ml   = bid % mc;
    int rest = bid / mc;
    int bx   = rest % nbx;
    int zz   = rest / nbx;
    int m  = mbase + ml;
    float* C = covb + (size_t)ml * SMPL;
    int rowbase = p + bx * 64;
    int zoff = zz * 32;
    int bofp = rowoff(p);
    int bsp  = 64*(p>>6) + 80;

    __shared__ __align__(16) float As[32][68];   // k-major, 64 rows
    __shared__ __align__(16) float Bs[32][36];   // k-major, 32 rows

    int tid = threadIdx.x;
    int tx = tid & 7,  ty = tid >> 3;   // 8 col-quads x 32 row-pairs
    int c0 = tx * 4,   r0 = ty * 2;

    float4 acc0 = make_float4(0,0,0,0), acc1 = make_float4(0,0,0,0);

    float4 ra[2], rb1;
    #pragma unroll
    for (int t = 0; t < 2; ++t) {
        int idx = tid + t * 256;
        int ii = idx >> 3, c4 = (idx & 7) << 2;
        int gr = rowbase + ii;
        ra[t] = make_float4(0,0,0,0);
        if (gr < NN) ra[t] = *(const float4*)(C + rowoff(gr) + c4);
    }
    {
        int ii = tid >> 3, c4 = (tid & 7) << 2;
        rb1 = *(const float4*)(C + bofp + (zoff + ii) * bsp + c4);
    }

    for (int ks = 0; ks < p; ks += 32) {
        #pragma unroll
        for (int t = 0; t < 2; ++t) {
            int idx = tid + t * 256;
            int ii = idx >> 3, c4 = (idx & 7) << 2;
            As[c4+0][ii] = ra[t].x; As[c4+1][ii] = ra[t].y;
            As[c4+2][ii] = ra[t].z; As[c4+3][ii] = ra[t].w;
        }
        {
            int ii = tid >> 3, c4 = (tid & 7) << 2;
            Bs[c4+0][ii] = rb1.x; Bs[c4+1][ii] = rb1.y;
            Bs[c4+2][ii] = rb1.z; Bs[c4+3][ii] = rb1.w;
        }
        __syncthreads();
        int kn = ks + 32;
        if (kn < p) {
            #pragma unroll
            for (int t = 0; t < 2; ++t) {
                int idx = tid + t * 256;
                int ii = idx >> 3, c4 = (idx & 7) << 2;
                int gr = rowbase + ii;
                ra[t] = make_float4(0,0,0,0);
                if (gr < NN) ra[t] = *(const float4*)(C + rowoff(gr) + kn + c4);
            }
            {
                int ii = tid >> 3, c4 = (tid & 7) << 2;
                rb1 = *(const float4*)(C + bofp + (zoff + ii) * bsp + kn + c4);
            }
        }
        #pragma unroll
        for (int k = 0; k < 32; ++k) {
            float4 bv = *(const float4*)&Bs[k][c0];
            float2 av = *(const float2*)&As[k][r0];
            fma4(acc0, av.x, bv);
            fma4(acc1, av.y, bv);
        }
        __syncthreads();
    }

    int jcol = p + zoff + c0;
    float sigma2 = scal[m];
    float eta    = scal[NSAMP + m];
    float ilZ    = scal[2*NSAMP + m];
    float ilN    = scal[3*NSAMP + m];
    float4 xa = *(const float4*)(x + 2*jcol);
    float4 xb = *(const float4*)(x + 2*jcol + 4);
    int g0 = rowbase + r0;
    #pragma unroll
    for (int rr = 0; rr < 2; ++rr) {
        int g = g0 + rr;
        if (g < NN) {
            float xi0 = x[2*g]   * ilZ;
            float xi1 = x[2*g+1] * ilN;
            float v[4]; float d0, d1;
            d0 = xa.x*ilZ - xi0; d1 = xa.y*ilN - xi1; v[0] = eta*__expf(-0.5f*(d0*d0+d1*d1));
            d0 = xa.z*ilZ - xi0; d1 = xa.w*ilN - xi1; v[1] = eta*__expf(-0.5f*(d0*d0+d1*d1));
            d0 = xb.x*ilZ - xi0; d1 = xb.y*ilN - xi1; v[2] = eta*__expf(-0.5f*(d0*d0+d1*d1));
            d0 = xb.z*ilZ - xi0; d1 = xb.w*ilN - xi1; v[3] = eta*__expf(-0.5f*(d0*d0+d1*d1));
            #pragma unroll
            for (int qq = 0; qq < 4; ++qq) if (jcol + qq == g) v[qq] += sigma2;
            const float4 ac = (rr == 0) ? acc0 : acc1;
            float* cp = C + rowoff(g) + jcol;
            float4 u;
            u.x = v[0] - ac.x; u.y = v[1] - ac.y; u.z = v[2] - ac.z; u.w = v[3] - ac.w;
            *(float4*)cp = u;
        }
    }
}

// ---------------- fused diag-factor + panel TRSM ----------------
__global__ __launch_bounds__(128)
void trsm_kernel(float* __restrict__ covb, float* __restrict__ bvec,
                 float* __restrict__ stats, int mbase, int p, int mc)
{
    int bid = blockIdx.x;
    int ml  = bid % mc;
    int bx  = bid / mc;
    int m  = mbase + ml;
    float* C = covb + (size_t)ml * SMPL;
    __shared__ __align__(16) float Tl[NB][68];
    __shared__ float rs_s[NB], sol_s[NB];
    int tid = threadIdx.x;
    int bofp = rowoff(p);
    int bsp  = 64*(p>>6) + 80;

    // preload solve rows (global loads in flight while wave 0 factors)
    int r0 = p + NB + bx * 128 + tid;
    bool have = (r0 < NN);
    float l[NB];
    int roff = have ? rowoff(r0) : 0;
    if (have) {
        const float* rowp = C + roff + p;
        #pragma unroll
        for (int q = 0; q < NB/4; ++q) {
            float4 v = *(const float4*)(rowp + 4*q);
            l[4*q] = v.x; l[4*q+1] = v.y; l[4*q+2] = v.z; l[4*q+3] = v.w;
        }
    }

    // ---- in-block diag factor (wave 0), verbatim diag arithmetic
    if (tid < 64) {
        int r = tid;
        float row[NB];
        const float* src = C + bofp + r * bsp + p;
        #pragma unroll
        for (int q = 0; q < NB/4; ++q) {
            float4 v = *(const float4*)(src + 4*q);
            row[4*q+0] = v.x; row[4*q+1] = v.y; row[4*q+2] = v.z; row[4*q+3] = v.w;
        }
        float b = bvec[(size_t)m * NN + p + r];
        float quad_add = 0.f, my_d = 1.f, my_rs = 0.f, my_sol = 0.f;
        #pragma unroll
        for (int j = 0; j < NB; ++j) {
            float dj = fmaxf(bcastf(row[j], j), 1e-30f);
            float rs = rsqrtf(dj);
            if (r == j) my_d = dj;
            row[j] *= rs;                       // row[j] = L[r][j] for r>=j
            float sj = bcastf(b, j) * rs;
            quad_add = fmaf(sj, sj, quad_add);
            b = fmaf(-row[j], sj, b);
            if (r == j) { my_rs = rs; my_sol = sj; }
            #pragma unroll
            for (int c = j + 1; c < NB; ++c) {
                float s = bcastf(row[j], c);    // = L[c][j]
                row[c] = fmaf(-row[j], s, row[c]);
            }
        }
        #pragma unroll
        for (int q = 0; q < NB/4; ++q) {
            float4 v; v.x = row[4*q]; v.y = row[4*q+1]; v.z = row[4*q+2]; v.w = row[4*q+3];
            *(float4*)&Tl[r][4*q] = v;
        }
        rs_s[r]  = my_rs;
        sol_s[r] = my_sol;
        if (bx == 0) {
            float ldv = logf(my_d);
            #pragma unroll
            for (int off = 32; off > 0; off >>= 1) ldv += __shfl_down(ldv, off);
            if (r == 0) {
                stats[2*m]   += quad_add;
                stats[2*m+1] += ldv;
            }
        }
    }
    __syncthreads();

    if (!have) return;
    float* rowp = C + roff + p;
    #pragma unroll
    for (int j = 0; j < NB; ++j) {
        float s0 = l[j], s1 = 0.f, s2 = 0.f, s3 = 0.f;
        int c = 0;
        #pragma unroll
        for (; c + 4 <= j; c += 4) {
            float4 t = *(const float4*)&Tl[j][c];
            s0 = fmaf(-l[c],   t.x, s0);
            s1 = fmaf(-l[c+1], t.y, s1);
            s2 = fmaf(-l[c+2], t.z, s2);
            s3 = fmaf(-l[c+3], t.w, s3);
        }
        #pragma unroll
        for (; c < j; ++c) s0 = fmaf(-l[c], Tl[j][c], s0);
        l[j] = ((s0 + s1) + (s2 + s3)) * rs_s[j];
    }
    #pragma unroll
    for (int q = 0; q < NB/4; ++q) {
        float4 v; v.x = l[4*q]; v.y = l[4*q+1]; v.z = l[4*q+2]; v.w = l[4*q+3];
        *(float4*)(rowp + 4*q) = v;
    }
    float b0 = 0.f, b1 = 0.f, b2 = 0.f, b3 = 0.f;
    #pragma unroll
    for (int j = 0; j < NB; j += 4) {
        b0 = fmaf(l[j],   sol_s[j],   b0);
        b1 = fmaf(l[j+1], sol_s[j+1], b1);
        b2 = fmaf(l[j+2], sol_s[j+2], b2);
        b3 = fmaf(l[j+3], sol_s[j+3], b3);
    }
    bvec[(size_t)m * NN + r0] -= ((b0 + b1) + (b2 + b3));
}

// ---------------- tail SYRK: one block per sample, full K, reduce-in-place ----------------
// r27: split-K=4 + psq partials + finish-side reduce is replaced by a single
// owner block per sample (K=0..896, pipelined staging hides L3 latency even
// at 1 wave/SIMD) whose epilogue does tsq -= acc in place. psq (16MB) is
// deleted; finish's reduce phase collapses to a straight tsq read.
__global__ __launch_bounds__(256)
void tailsyrk_kernel(const float* __restrict__ covb, float* __restrict__ tsq)
{
    int ml = blockIdx.x;
    const float* C = covb + (size_t)ml * SMPL;
    float* T = tsq + (size_t)ml * TSQN;

    __shared__ __align__(16) float As[32][132];
    int tid = threadIdx.x;
    int tx = tid & 15, ty = tid >> 4;
    int c0 = tx * 8, r0 = ty * 8;

    float4 acc[8][2];
    #pragma unroll
    for (int r = 0; r < 8; ++r) { acc[r][0] = make_float4(0,0,0,0); acc[r][1] = make_float4(0,0,0,0); }

    float4 ra[4];
    #pragma unroll
    for (int t = 0; t < 4; ++t) {
        int idx = tid + t * 256;
        int ii = idx >> 3, c4 = (idx & 7) << 2;
        ra[t] = *(const float4*)(C + rowoff(CROSS + ii) + c4);
    }

    for (int ks = 0; ks < CROSS; ks += 32) {
        #pragma unroll
        for (int t = 0; t < 4; ++t) {
            int idx = tid + t * 256;
            int ii = idx >> 3, c4 = (idx & 7) << 2;
            As[c4+0][ii] = ra[t].x; As[c4+1][ii] = ra[t].y;
            As[c4+2][ii] = ra[t].z; As[c4+3][ii] = ra[t].w;
        }
        __syncthreads();
        int kn = ks + 32;
        if (kn < CROSS) {
            #pragma unroll
            for (int t = 0; t < 4; ++t) {
                int idx = tid + t * 256;
                int ii = idx >> 3, c4 = (idx & 7) << 2;
                ra[t] = *(const float4*)(C + rowoff(CROSS + ii) + kn + c4);
            }
        }
        #pragma unroll
        for (int k = 0; k < 32; ++k) {
            float4 b0 = *(const float4*)&As[k][c0];
            float4 b1 = *(const float4*)&As[k][c0 + 4];
            float4 a0 = *(const float4*)&As[k][r0];
            float4 a1 = *(const float4*)&As[k][r0 + 4];
            float ar[8] = {a0.x, a0.y, a0.z, a0.w, a1.x, a1.y, a1.z, a1.w};
            #pragma unroll
            for (int r = 0; r < 8; ++r) {
                fma4(acc[r][0], ar[r], b0);
                fma4(acc[r][1], ar[r], b1);
            }
        }
        __syncthreads();
    }

    // single-owner reduce in place: T -= acc
    #pragma unroll
    for (int r = 0; r < 8; ++r) {
        float* cp = T + (r0 + r) * TB + c0;
        float4 u0 = *(float4*)cp;
        float4 u1 = *((float4*)cp + 1);
        u0.x -= acc[r][0].x; u0.y -= acc[r][0].y; u0.z -= acc[r][0].z; u0.w -= acc[r][0].w;
        u1.x -= acc[r][1].x; u1.y -= acc[r][1].y; u1.z -= acc[r][1].z; u1.w -= acc[r][1].w;
        *(float4*)cp = u0;
        *((float4*)cp + 1) = u1;
    }
}

// ---------------- per-sample finish (tsq already reduced) ----------------
__global__ __launch_bounds__(512)
void finish_kernel(const float* __restrict__ tsq, const float* __restrict__ bvec,
                   const float* __restrict__ stats, float* __restrict__ out,
                   const float* __restrict__ scal, int mbase)
{
    int ml = blockIdx.x;
    int m  = mbase + ml;
    const float* T = tsq + (size_t)ml * TSQN;
    __shared__ __align__(16) float A11[NB][68];   // tail 11; after TRSM: k-major L21 (Ps)
    __shared__ __align__(16) float A21[NB][68];   // tail rows 64..127, cols 0..63
    __shared__ __align__(16) float A22[NB][68];
    __shared__ float rs_s[NB], sol_s[NB];
    __shared__ float bt[TB];
    __shared__ float s_quad, s_ld;
    int tid = threadIdx.x;

    if (tid < TB) bt[tid] = bvec[(size_t)m * NN + CROSS + tid];
    if (tid == 0) { s_quad = 0.f; s_ld = 0.f; }

    // ---- load the (already reduced) tail into LDS ----
    #pragma unroll
    for (int u = 0; u < 6; ++u) {
        int f   = tid + u * 512;
        int i   = (f & 1023) >> 4;
        int c4  = (f & 15) << 2;
        int blk = f >> 10;
        int ti  = (blk == 0) ? i : (64 + i);         // tail-local row
        int tc  = (blk == 2) ? (64 + c4) : c4;       // tail-local col
        float4 t = *(const float4*)(T + ti * TB + tc);
        float* dst = (blk == 0) ? &A11[i][c4] : ((blk == 1) ? &A21[i][c4] : &A22[i][c4]);
        *(float4*)dst = t;
    }
    __syncthreads();

    // ---- factor A11 (64x64), scaled rows back into A11 ----
    if (tid < 64) {
        int r = tid;
        float row[NB];
        #pragma unroll
        for (int q = 0; q < NB/4; ++q) {
            float4 v = *(const float4*)&A11[r][4*q];
            row[4*q+0] = v.x; row[4*q+1] = v.y; row[4*q+2] = v.z; row[4*q+3] = v.w;
        }
        float b = bt[r];
        float quad_add = 0.f, my_d = 1.f;
        #pragma unroll
        for (int j = 0; j < NB; ++j) {
            float dj = fmaxf(bcastf(row[j], j), 1e-30f);
            float rs = rsqrtf(dj);
            if (r == j) my_d = dj;
            row[j] *= rs;
            float sj = bcastf(b, j) * rs;
            quad_add = fmaf(sj, sj, quad_add);
            b = fmaf(-row[j], sj, b);
            if (r == j) { rs_s[j] = rs; sol_s[j] = sj; }
            #pragma unroll
            for (int c = j + 1; c < NB; ++c) {
                float s = bcastf(row[j], c);
                row[c] = fmaf(-row[j], s, row[c]);
            }
        }
        #pragma unroll
        for (int q = 0; q < NB/4; ++q) {
            float4 v; v.x = row[4*q]; v.y = row[4*q+1]; v.z = row[4*q+2]; v.w = row[4*q+3];
            *(float4*)&A11[r][4*q] = v;
        }
        float ldv = logf(my_d);
        #pragma unroll
        for (int off = 32; off > 0; off >>= 1) ldv += __shfl_down(ldv, off);
        if (r == 0) { s_quad += quad_add; s_ld += ldv; }
    }
    __syncthreads();

    // ---- TRSM: rows of A21 (wave 1); result transposed into A11 (k-major Ps) ----
    if (tid >= 64 && tid < 128) {
        int rr = tid - 64;
        float l[NB];
        #pragma unroll
        for (int q = 0; q < NB/4; ++q) {
            float4 v = *(const float4*)&A21[rr][4*q];
            l[4*q] = v.x; l[4*q+1] = v.y; l[4*q+2] = v.z; l[4*q+3] = v.w;
        }
        #pragma unroll
        for (int j = 0; j < NB; ++j) {
            float s0 = l[j], s1 = 0.f, s2 = 0.f, s3 = 0.f;
            int c = 0;
            #pragma unroll
            for (; c + 4 <= j; c += 4) {
                float4 t = *(const float4*)&A11[j][c];
                s0 = fmaf(-l[c],   t.x, s0);
                s1 = fmaf(-l[c+1], t.y, s1);
                s2 = fmaf(-l[c+2], t.z, s2);
                s3 = fmaf(-l[c+3], t.w, s3);
            }
            #pragma unroll
            for (; c < j; ++c) s0 = fmaf(-l[c], A11[j][c], s0);
            l[j] = ((s0 + s1) + (s2 + s3)) * rs_s[j];
        }
        // A11 is dead now; single-wave program order makes this race-free.
        #pragma unroll
        for (int k = 0; k < NB; ++k) A11[k][rr] = l[k];   // Ps[k][rr]
        float bacc = 0.f;
        #pragma unroll
        for (int j = 0; j < NB; ++j) bacc = fmaf(l[j], sol_s[j], bacc);
        bt[64 + rr] -= bacc;
    }
    __syncthreads();

    // ---- SYRK: A22 -= L21 * L21^T, k-major Ps (= A11), conflict-free ----
    for (int idx = tid; idx < 64 * 16; idx += 512) {
        int i  = idx >> 4;
        int j4 = (idx & 15) << 2;
        if (j4 > i) continue;
        float4 a = make_float4(0,0,0,0);
        #pragma unroll 8
        for (int k = 0; k < NB; ++k) {
            float4 pj = *(const float4*)&A11[k][j4];
            fma4(a, A11[k][i], pj);
        }
        float* cp = &A22[i][j4];
        float4 uu = *(float4*)cp;
        uu.x -= a.x; uu.y -= a.y; uu.z -= a.z; uu.w -= a.w;
        *(float4*)cp = uu;
    }
    __syncthreads();

    // ---- factor A22 (64x64); only logdet + quad needed ----
    if (tid < 64) {
        int r = tid;
        float row[NB];
        #pragma unroll
        for (int q = 0; q < NB/4; ++q) {
            float4 v = *(const float4*)&A22[r][4*q];
            row[4*q+0] = v.x; row[4*q+1] = v.y; row[4*q+2] = v.z; row[4*q+3] = v.w;
        }
        float b = bt[64 + r];
        float quad_add = 0.f, my_d = 1.f;
        #pragma unroll
        for (int j = 0; j < NB; ++j) {
            float dj = fmaxf(bcastf(row[j], j), 1e-30f);
            float rs = rsqrtf(dj);
            if (r == j) my_d = dj;
            row[j] *= rs;
            float sj = bcastf(b, j) * rs;
            quad_add = fmaf(sj, sj, quad_add);
            b = fmaf(-row[j], sj, b);
            #pragma unroll
            for (int c = j + 1; c < NB; ++c) {
                float s = bcastf(row[j], c);
                row[c] = fmaf(-row[j], s, row[c]);
            }
        }
        float ldv = logf(my_d);
        #pragma unroll
        for (int off = 32; off > 0; off >>= 1) ldv += __shfl_down(ldv, off);
        if (r == 0) { s_quad += quad_add; s_ld += ldv; }
    }
    __syncthreads();

    if (tid == 0) {
        float qt = stats[2*m]   + s_quad;
        float lt = stats[2*m+1] + s_ld;
        out[m] = -0.5f * (qt + lt + (float)NN * LOG2PI) + scal[5*NSAMP + m];
    }
}

extern "C" void kernel_launch(void* const* d_in, const int* in_sizes, int n_in,
                              void* d_out, int out_size, void* d_ws, size_t ws_size,
                              hipStream_t stream)
{
    const float* x   = (const float*)d_in[0];
    const float* y   = (const float*)d_in[1];
    const float* z   = (const float*)d_in[2];
    const float* qbm = (const float*)d_in[3];
    const float* qbs = (const float*)d_in[4];
    const float* qsm = (const float*)d_in[5];
    const float* qss = (const float*)d_in[6];
    const float* qem = (const float*)d_in[7];
    const float* qes = (const float*)d_in[8];
    const float* qzm = (const float*)d_in[9];
    const float* qzs = (const float*)d_in[10];
    const float* qnm = (const float*)d_in[11];
    const float* qns = (const float*)d_in[12];
    float* out  = (float*)d_out;
    float* ws   = (float*)d_ws;

    // workspace layout (floats)
    float* scal   = ws;                                   // 384 used
    float* bvec   = ws + 1024;                            // 64*1024
    float* stats  = ws + 1024 + NSAMP*NN;                 // 128 used, 512 res
    float* tsq    = ws + 1024 + NSAMP*NN + 512;           // 64 * 128*128 (4MB)
    float* cov    = tsq + (size_t)NSAMP * TSQN;           // 64 * SMPL (147MB banded)
    size_t headF  = 1024 + (size_t)NSAMP*NN + 512;

    scal_kernel<<<1, 64, 0, stream>>>(z, qbm, qbs, qsm, qss, qem, qes, qzm, qzs, qnm, qns, scal);

    size_t availF = ws_size / 4;
    size_t perM   = (size_t)SMPL + TSQN;   // per-sample footprint
    int mc_max = NSAMP;
    if (availF < headF + (size_t)NSAMP * perM) {
        size_t rem = (availF > headF) ? (availF - headF) : 0;
        mc_max = (int)(rem / perM);
        if (mc_max < 1) mc_max = 1;
        if (mc_max > NSAMP) mc_max = NSAMP;
    }

    for (int mb = 0; mb < NSAMP; mb += mc_max) {
        int mc = NSAMP - mb; if (mc > mc_max) mc = mc_max;
        covslim_kernel<<<dim3(80 * mc), 256, 0, stream>>>(cov, tsq, scal, x, y, bvec, stats, mb, mc);
        for (int q = 0; q < CROSS / NB; ++q) {   // panels p = 0..832
            int p = q * NB;
            if (q > 0) {
                int rows = NN - p;
                int rt128 = (rows + 127) / 128;
                if (rt128 * mc >= 448) {
                    update_kernel<<<dim3(rt128 * mc), 256, 0, stream>>>(cov, scal, x, mb, p, mc);
                } else {
                    int rt64 = (rows + 63) / 64;
                    update_small_kernel<<<dim3(rt64 * mc * 2), 256, 0, stream>>>(cov, scal, x, mb, p, mc, rt64);
                }
            }
            int rb = NN - p - NB;
            int rtiles = (rb + 127) / 128;
            trsm_kernel<<<dim3(rtiles * mc), 128, 0, stream>>>(cov, bvec, stats, mb, p, mc);
        }
        tailsyrk_kernel<<<dim3(mc), 256, 0, stream>>>(cov, tsq);
        finish_kernel<<<mc, 512, 0, stream>>>(tsq, bvec, stats, out, scal, mb);
    }
}

// Round 17
// 1161.127 us; speedup vs baseline: 2.0303x; 2.0303x over previous
//
#include <hip/hip_runtime.h>
#include <math.h>

#define NN 1024           // N (logical)
#define NB 64             // panel width
#define TB 128            // tail handled by tailsyrk+finish
#define CROSS (NN - TB)   // 896: panel loop covers p < CROSS
#define NSAMP 64          // n_mc
// r25: banded-packed cov. Band b (rows 64b..64b+63) stores cols 0..64(b+1)+15
// (stride bs(b)=64b+80). Per-sample 573440 floats -> 64 samples = 147MB,
// ONE L3-resident batch.
// r28: verbatim revert to the r26 kernel (1153.7us, absmax 0). r27's
// single-owner tailsyrk + reduce-free finish regressed 2x: finish's load
// phase dropped from 30 concurrent loads/thread to 6, reading lines left
// dirty by tailsyrk's RMW -> 10 GB/s latency stall (280us), plus a 30ms
// copyBuffer appeared in the dispatch stream. Split-K psq's redundant
// traffic is cheaper than low-MLP dirty-line reads.
#define SMPL 573440
#define TSQN (TB*TB)      // dense tail square per sample (finish input)
#define PSQN (TB*512)     // tailsyrk split-K partials per sample

#define CCONST  (-0.91893853320467274f)   // -0.5*log(2*pi)
#define LOG2PI  (1.8378770664093453f)

__device__ __forceinline__ int rowoff(int i) {
    int b = i >> 6;
    return (2048*b + 3072)*b + (i & 63)*(64*b + 80);
}
__device__ __forceinline__ float bcastf(float v, int lane) {
    return __int_as_float(__builtin_amdgcn_readlane(__float_as_int(v), lane));
}
__device__ __forceinline__ float softplus_d(float v) {
    return (v > 20.f ? v : log1pf(expf(v))) + 1e-7f;
}
__device__ __forceinline__ float log_normal_f(float v, float mean, float s, float eps) {
    float d = v - mean;
    return -d * d / (2.f * s * s + eps) - logf(s) + CCONST;
}
__device__ __forceinline__ float log_lognormal_f(float v, float mean, float s) {
    float lv = logf(v);
    float d = lv - mean;
    return -d * d / (2.f * s * s + 1e-6f) - lv - logf(s) + CCONST;
}
__device__ __forceinline__ void fma4(float4& c, float a, const float4& b) {
    c.x = fmaf(a, b.x, c.x); c.y = fmaf(a, b.y, c.y);
    c.z = fmaf(a, b.z, c.z); c.w = fmaf(a, b.w, c.w);
}

// ---------------- per-sample scalars ----------------
__global__ void scal_kernel(const float* __restrict__ z,
    const float* qbm, const float* qbs, const float* qsm, const float* qss,
    const float* qem, const float* qes, const float* qzm, const float* qzs,
    const float* qnm, const float* qns, float* __restrict__ scal)
{
    int m = threadIdx.x;
    if (m >= NSAMP) return;
    float z0 = z[m*5+0], z1 = z[m*5+1], z2 = z[m*5+2], z3 = z[m*5+3], z4 = z[m*5+4];
    float spb = softplus_d(qbs[0]);
    float sps = softplus_d(qss[0]);
    float spe = softplus_d(qes[0]);
    float spz = softplus_d(qzs[0]);
    float spn = softplus_d(qns[0]);
    float sigma2 = expf(z0 * sps + qsm[0]);
    float beta   = z1 * spb + qbm[0];
    float eta    = expf(z2 * spe + qem[0]);
    float lsZ    = expf(z3 * spz + qzm[0]);
    float lsN    = expf(z4 * spn + qnm[0]);
    float s0 = softplus_d(sqrtf(logf(2.f)));
    float lp = log_normal_f(beta, 0.f, 1.f, 1e-5f)
             + log_lognormal_f(sigma2, 1.f, s0)
             + log_lognormal_f(eta,    1.f, s0)
             + log_lognormal_f(lsZ,    1.f, s0)
             + log_lognormal_f(lsN,    1.f, s0);
    float lq = log_normal_f(beta, qbm[0], spb, 1e-5f)
             + log_lognormal_f(sigma2, qsm[0], sps)
             + log_lognormal_f(eta,    qem[0], spe)
             + log_lognormal_f(lsZ,    qzm[0], spz)
             + log_lognormal_f(lsN,    qnm[0], spn);
    scal[m]           = sigma2;
    scal[NSAMP + m]   = eta;
    scal[2*NSAMP + m] = 1.f / lsZ;
    scal[3*NSAMP + m] = 1.f / lsN;
    scal[4*NSAMP + m] = beta;
    scal[5*NSAMP + m] = lp - lq;
}

// ---------------- slim covariance build + bvec/stats init ----------------
__global__ __launch_bounds__(256)
void covslim_kernel(float* __restrict__ cov, float* __restrict__ tsq,
                    const float* __restrict__ scal,
                    const float* __restrict__ x, const float* __restrict__ y,
                    float* __restrict__ bvec, float* __restrict__ stats, int mbase)
{
    int ml = blockIdx.y;
    int m  = mbase + ml;
    float sigma2 = scal[m];
    float eta    = scal[NSAMP + m];
    float ilZ    = scal[2*NSAMP + m];
    float ilN    = scal[3*NSAMP + m];
    float* C = cov + (size_t)ml * SMPL;
    int tid = threadIdx.x;

    if (blockIdx.x == 0 && tid == 0) { stats[2*m] = 0.f; stats[2*m+1] = 0.f; }

    if (blockIdx.x < 64) {
        // stripe: 16 rows x 64 cols per block (lower triangle only)
        int i  = blockIdx.x * 16 + (tid >> 4);
        int j0 = (tid & 15) * 4;
        if ((tid & 15) == 0) bvec[(size_t)m * NN + i] = y[i] - scal[4*NSAMP + m];
        if (j0 > i) return;
        float xi0 = x[2*i]   * ilZ;
        float xi1 = x[2*i+1] * ilN;
        float4 xa = *(const float4*)(x + 2*j0);
        float4 xb = *(const float4*)(x + 2*j0 + 4);
        float v[4]; float d0, d1;
        d0 = xa.x*ilZ - xi0; d1 = xa.y*ilN - xi1; v[0] = eta*__expf(-0.5f*(d0*d0+d1*d1));
        d0 = xa.z*ilZ - xi0; d1 = xa.w*ilN - xi1; v[1] = eta*__expf(-0.5f*(d0*d0+d1*d1));
        d0 = xb.x*ilZ - xi0; d1 = xb.y*ilN - xi1; v[2] = eta*__expf(-0.5f*(d0*d0+d1*d1));
        d0 = xb.z*ilZ - xi0; d1 = xb.w*ilN - xi1; v[3] = eta*__expf(-0.5f*(d0*d0+d1*d1));
        #pragma unroll
        for (int q = 0; q < 4; ++q) if (j0 + q == i) v[q] += sigma2;
        float* row = C + rowoff(i);
        if (j0 + 3 <= i) {
            float4 o; o.x = v[0]; o.y = v[1]; o.z = v[2]; o.w = v[3];
            *(float4*)(row + j0) = o;
        } else {
            #pragma unroll
            for (int q = 0; q < 4; ++q) if (j0 + q <= i) row[j0+q] = v[q];
        }
    } else {
        // tail: 8 rows x 128 cols per block -> dense tsq[128][128]
        int bx2 = blockIdx.x - 64;                 // 0..15
        int tr  = bx2 * 8 + (tid >> 5);            // 0..127 tail-local row
        int tc  = (tid & 31) * 4;                  // 0..124 tail-local col
        int i   = CROSS + tr;
        int j0  = CROSS + tc;
        float xi0 = x[2*i]   * ilZ;
        float xi1 = x[2*i+1] * ilN;
        float4 xa = *(const float4*)(x + 2*j0);
        float4 xb = *(const float4*)(x + 2*j0 + 4);
        float v[4]; float d0, d1;
        d0 = xa.x*ilZ - xi0; d1 = xa.y*ilN - xi1; v[0] = eta*__expf(-0.5f*(d0*d0+d1*d1));
        d0 = xa.z*ilZ - xi0; d1 = xa.w*ilN - xi1; v[1] = eta*__expf(-0.5f*(d0*d0+d1*d1));
        d0 = xb.x*ilZ - xi0; d1 = xb.y*ilN - xi1; v[2] = eta*__expf(-0.5f*(d0*d0+d1*d1));
        d0 = xb.z*ilZ - xi0; d1 = xb.w*ilN - xi1; v[3] = eta*__expf(-0.5f*(d0*d0+d1*d1));
        #pragma unroll
        for (int q = 0; q < 4; ++q) if (j0 + q == i) v[q] += sigma2;
        float4 o; o.x = v[0]; o.y = v[1]; o.z = v[2]; o.w = v[3];
        *(float4*)(tsq + (size_t)ml * TSQN + tr * TB + tc) = o;
    }
}

// ---------------- left-looking block-column update (GEMM, K = p) ----------------
// r26: software-pipelined staging (works now that the set is L3-resident).
__global__ __launch_bounds__(256)
void update_kernel(float* __restrict__ covb, const float* __restrict__ scal,
                   const float* __restrict__ x, int mbase, int p, int mc)
{
    int bid = blockIdx.x;
    int ml  = bid % mc;
    int bx  = bid / mc;
    int m  = mbase + ml;
    float* C = covb + (size_t)ml * SMPL;
    int rowbase = p + bx * 128;
    int bofp = rowoff(p);
    int bsp  = 64*(p>>6) + 80;

    __shared__ __align__(16) float As[32][132];  // k-major, 128 rows
    __shared__ __align__(16) float Bs[32][68];   // k-major, 64 rows

    int tid = threadIdx.x;
    int tx = tid & 7,  ty = tid >> 3;
    int c0 = tx * 8,   r0 = ty * 4;

    float4 acc[4][2];
    #pragma unroll
    for (int r = 0; r < 4; ++r) { acc[r][0] = make_float4(0,0,0,0); acc[r][1] = make_float4(0,0,0,0); }

    // prefetch k-step 0 into registers
    float4 ra[4], rb[2];
    #pragma unroll
    for (int t = 0; t < 4; ++t) {
        int idx = tid + t * 256;
        int ii = idx >> 3, c4 = (idx & 7) << 2;
        int gr = rowbase + ii;
        ra[t] = make_float4(0,0,0,0);
        if (gr < NN) ra[t] = *(const float4*)(C + rowoff(gr) + c4);
    }
    #pragma unroll
    for (int t = 0; t < 2; ++t) {
        int idx = tid + t * 256;
        int ii = idx >> 3, c4 = (idx & 7) << 2;
        rb[t] = *(const float4*)(C + bofp + ii * bsp + c4);
    }

    for (int ks = 0; ks < p; ks += 32) {
        #pragma unroll
        for (int t = 0; t < 4; ++t) {
            int idx = tid + t * 256;
            int ii = idx >> 3, c4 = (idx & 7) << 2;
            As[c4+0][ii] = ra[t].x; As[c4+1][ii] = ra[t].y;
            As[c4+2][ii] = ra[t].z; As[c4+3][ii] = ra[t].w;
        }
        #pragma unroll
        for (int t = 0; t < 2; ++t) {
            int idx = tid + t * 256;
            int ii = idx >> 3, c4 = (idx & 7) << 2;
            Bs[c4+0][ii] = rb[t].x; Bs[c4+1][ii] = rb[t].y;
            Bs[c4+2][ii] = rb[t].z; Bs[c4+3][ii] = rb[t].w;
        }
        __syncthreads();
        int kn = ks + 32;
        if (kn < p) {
            #pragma unroll
            for (int t = 0; t < 4; ++t) {
                int idx = tid + t * 256;
                int ii = idx >> 3, c4 = (idx & 7) << 2;
                int gr = rowbase + ii;
                ra[t] = make_float4(0,0,0,0);
                if (gr < NN) ra[t] = *(const float4*)(C + rowoff(gr) + kn + c4);
            }
            #pragma unroll
            for (int t = 0; t < 2; ++t) {
                int idx = tid + t * 256;
                int ii = idx >> 3, c4 = (idx & 7) << 2;
                rb[t] = *(const float4*)(C + bofp + ii * bsp + kn + c4);
            }
        }
        #pragma unroll
        for (int k = 0; k < 32; ++k) {
            float4 b0 = *(const float4*)&Bs[k][c0];
            float4 b1 = *(const float4*)&Bs[k][c0 + 4];
            float4 a0 = *(const float4*)&As[k][r0];
            float ar[4] = {a0.x, a0.y, a0.z, a0.w};
            #pragma unroll
            for (int r = 0; r < 4; ++r) {
                fma4(acc[r][0], ar[r], b0);
                fma4(acc[r][1], ar[r], b1);
            }
        }
        __syncthreads();
    }

    int jcol = p + c0;
    float sigma2 = scal[m];
    float eta    = scal[NSAMP + m];
    float ilZ    = scal[2*NSAMP + m];
    float ilN    = scal[3*NSAMP + m];
    float4 xa0 = *(const float4*)(x + 2*jcol);
    float4 xb0 = *(const float4*)(x + 2*jcol + 4);
    float4 xa1 = *(const float4*)(x + 2*jcol + 8);
    float4 xb1 = *(const float4*)(x + 2*jcol + 12);
    #pragma unroll
    for (int r = 0; r < 4; ++r) {
        int g = rowbase + r0 + r;
        if (g < NN) {
            float xi0 = x[2*g]   * ilZ;
            float xi1 = x[2*g+1] * ilN;
            float v[8]; float d0, d1;
            d0 = xa0.x*ilZ - xi0; d1 = xa0.y*ilN - xi1; v[0] = eta*__expf(-0.5f*(d0*d0+d1*d1));
            d0 = xa0.z*ilZ - xi0; d1 = xa0.w*ilN - xi1; v[1] = eta*__expf(-0.5f*(d0*d0+d1*d1));
            d0 = xb0.x*ilZ - xi0; d1 = xb0.y*ilN - xi1; v[2] = eta*__expf(-0.5f*(d0*d0+d1*d1));
            d0 = xb0.z*ilZ - xi0; d1 = xb0.w*ilN - xi1; v[3] = eta*__expf(-0.5f*(d0*d0+d1*d1));
            d0 = xa1.x*ilZ - xi0; d1 = xa1.y*ilN - xi1; v[4] = eta*__expf(-0.5f*(d0*d0+d1*d1));
            d0 = xa1.z*ilZ - xi0; d1 = xa1.w*ilN - xi1; v[5] = eta*__expf(-0.5f*(d0*d0+d1*d1));
            d0 = xb1.x*ilZ - xi0; d1 = xb1.y*ilN - xi1; v[6] = eta*__expf(-0.5f*(d0*d0+d1*d1));
            d0 = xb1.z*ilZ - xi0; d1 = xb1.w*ilN - xi1; v[7] = eta*__expf(-0.5f*(d0*d0+d1*d1));
            #pragma unroll
            for (int qq = 0; qq < 8; ++qq) if (jcol + qq == g) v[qq] += sigma2;
            float* cp = C + rowoff(g) + jcol;
            float4 u0, u1;
            u0.x = v[0] - acc[r][0].x; u0.y = v[1] - acc[r][0].y;
            u0.z = v[2] - acc[r][0].z; u0.w = v[3] - acc[r][0].w;
            u1.x = v[4] - acc[r][1].x; u1.y = v[5] - acc[r][1].y;
            u1.z = v[6] - acc[r][1].z; u1.w = v[7] - acc[r][1].w;
            *(float4*)cp = u0;
            *((float4*)cp + 1) = u1;
        }
    }
}

// ---------------- small-tile update for late panels ----------------
__global__ __launch_bounds__(256)
void update_small_kernel(float* __restrict__ covb, const float* __restrict__ scal,
                         const float* __restrict__ x, int mbase, int p, int mc, int nbx)
{
    int bid  = blockIdx.x;
    int ml   = bid % mc;
    int rest = bid / mc;
    int bx   = rest % nbx;
    int zz   = rest / nbx;
    int m  = mbase + ml;
    float* C = covb + (size_t)ml * SMPL;
    int rowbase = p + bx * 64;
    int zoff = zz * 32;
    int bofp = rowoff(p);
    int bsp  = 64*(p>>6) + 80;

    __shared__ __align__(16) float As[32][68];   // k-major, 64 rows
    __shared__ __align__(16) float Bs[32][36];   // k-major, 32 rows

    int tid = threadIdx.x;
    int tx = tid & 7,  ty = tid >> 3;   // 8 col-quads x 32 row-pairs
    int c0 = tx * 4,   r0 = ty * 2;

    float4 acc0 = make_float4(0,0,0,0), acc1 = make_float4(0,0,0,0);

    float4 ra[2], rb1;
    #pragma unroll
    for (int t = 0; t < 2; ++t) {
        int idx = tid + t * 256;
        int ii = idx >> 3, c4 = (idx & 7) << 2;
        int gr = rowbase + ii;
        ra[t] = make_float4(0,0,0,0);
        if (gr < NN) ra[t] = *(const float4*)(C + rowoff(gr) + c4);
    }
    {
        int ii = tid >> 3, c4 = (tid & 7) << 2;
        rb1 = *(const float4*)(C + bofp + (zoff + ii) * bsp + c4);
    }

    for (int ks = 0; ks < p; ks += 32) {
        #pragma unroll
        for (int t = 0; t < 2; ++t) {
            int idx = tid + t * 256;
            int ii = idx >> 3, c4 = (idx & 7) << 2;
            As[c4+0][ii] = ra[t].x; As[c4+1][ii] = ra[t].y;
            As[c4+2][ii] = ra[t].z; As[c4+3][ii] = ra[t].w;
        }
        {
            int ii = tid >> 3, c4 = (tid & 7) << 2;
            Bs[c4+0][ii] = rb1.x; Bs[c4+1][ii] = rb1.y;
            Bs[c4+2][ii] = rb1.z; Bs[c4+3][ii] = rb1.w;
        }
        __syncthreads();
        int kn = ks + 32;
        if (kn < p) {
            #pragma unroll
            for (int t = 0; t < 2; ++t) {
                int idx = tid + t * 256;
                int ii = idx >> 3, c4 = (idx & 7) << 2;
                int gr = rowbase + ii;
                ra[t] = make_float4(0,0,0,0);
                if (gr < NN) ra[t] = *(const float4*)(C + rowoff(gr) + kn + c4);
            }
            {
                int ii = tid >> 3, c4 = (tid & 7) << 2;
                rb1 = *(const float4*)(C + bofp + (zoff + ii) * bsp + kn + c4);
            }
        }
        #pragma unroll
        for (int k = 0; k < 32; ++k) {
            float4 bv = *(const float4*)&Bs[k][c0];
            float2 av = *(const float2*)&As[k][r0];
            fma4(acc0, av.x, bv);
            fma4(acc1, av.y, bv);
        }
        __syncthreads();
    }

    int jcol = p + zoff + c0;
    float sigma2 = scal[m];
    float eta    = scal[NSAMP + m];
    float ilZ    = scal[2*NSAMP + m];
    float ilN    = scal[3*NSAMP + m];
    float4 xa = *(const float4*)(x + 2*jcol);
    float4 xb = *(const float4*)(x + 2*jcol + 4);
    int g0 = rowbase + r0;
    #pragma unroll
    for (int rr = 0; rr < 2; ++rr) {
        int g = g0 + rr;
        if (g < NN) {
            float xi0 = x[2*g]   * ilZ;
            float xi1 = x[2*g+1] * ilN;
            float v[4]; float d0, d1;
            d0 = xa.x*ilZ - xi0; d1 = xa.y*ilN - xi1; v[0] = eta*__expf(-0.5f*(d0*d0+d1*d1));
            d0 = xa.z*ilZ - xi0; d1 = xa.w*ilN - xi1; v[1] = eta*__expf(-0.5f*(d0*d0+d1*d1));
            d0 = xb.x*ilZ - xi0; d1 = xb.y*ilN - xi1; v[2] = eta*__expf(-0.5f*(d0*d0+d1*d1));
            d0 = xb.z*ilZ - xi0; d1 = xb.w*ilN - xi1; v[3] = eta*__expf(-0.5f*(d0*d0+d1*d1));
            #pragma unroll
            for (int qq = 0; qq < 4; ++qq) if (jcol + qq == g) v[qq] += sigma2;
            const float4 ac = (rr == 0) ? acc0 : acc1;
            float* cp = C + rowoff(g) + jcol;
            float4 u;
            u.x = v[0] - ac.x; u.y = v[1] - ac.y; u.z = v[2] - ac.z; u.w = v[3] - ac.w;
            *(float4*)cp = u;
        }
    }
}

// ---------------- fused diag-factor + panel TRSM ----------------
__global__ __launch_bounds__(128)
void trsm_kernel(float* __restrict__ covb, float* __restrict__ bvec,
                 float* __restrict__ stats, int mbase, int p, int mc)
{
    int bid = blockIdx.x;
    int ml  = bid % mc;
    int bx  = bid / mc;
    int m  = mbase + ml;
    float* C = covb + (size_t)ml * SMPL;
    __shared__ __align__(16) float Tl[NB][68];
    __shared__ float rs_s[NB], sol_s[NB];
    int tid = threadIdx.x;
    int bofp = rowoff(p);
    int bsp  = 64*(p>>6) + 80;

    // preload solve rows (global loads in flight while wave 0 factors)
    int r0 = p + NB + bx * 128 + tid;
    bool have = (r0 < NN);
    float l[NB];
    int roff = have ? rowoff(r0) : 0;
    if (have) {
        const float* rowp = C + roff + p;
        #pragma unroll
        for (int q = 0; q < NB/4; ++q) {
            float4 v = *(const float4*)(rowp + 4*q);
            l[4*q] = v.x; l[4*q+1] = v.y; l[4*q+2] = v.z; l[4*q+3] = v.w;
        }
    }

    // ---- in-block diag factor (wave 0), verbatim diag arithmetic
    if (tid < 64) {
        int r = tid;
        float row[NB];
        const float* src = C + bofp + r * bsp + p;
        #pragma unroll
        for (int q = 0; q < NB/4; ++q) {
            float4 v = *(const float4*)(src + 4*q);
            row[4*q+0] = v.x; row[4*q+1] = v.y; row[4*q+2] = v.z; row[4*q+3] = v.w;
        }
        float b = bvec[(size_t)m * NN + p + r];
        float quad_add = 0.f, my_d = 1.f, my_rs = 0.f, my_sol = 0.f;
        #pragma unroll
        for (int j = 0; j < NB; ++j) {
            float dj = fmaxf(bcastf(row[j], j), 1e-30f);
            float rs = rsqrtf(dj);
            if (r == j) my_d = dj;
            row[j] *= rs;                       // row[j] = L[r][j] for r>=j
            float sj = bcastf(b, j) * rs;
            quad_add = fmaf(sj, sj, quad_add);
            b = fmaf(-row[j], sj, b);
            if (r == j) { my_rs = rs; my_sol = sj; }
            #pragma unroll
            for (int c = j + 1; c < NB; ++c) {
                float s = bcastf(row[j], c);    // = L[c][j]
                row[c] = fmaf(-row[j], s, row[c]);
            }
        }
        #pragma unroll
        for (int q = 0; q < NB/4; ++q) {
            float4 v; v.x = row[4*q]; v.y = row[4*q+1]; v.z = row[4*q+2]; v.w = row[4*q+3];
            *(float4*)&Tl[r][4*q] = v;
        }
        rs_s[r]  = my_rs;
        sol_s[r] = my_sol;
        if (bx == 0) {
            float ldv = logf(my_d);
            #pragma unroll
            for (int off = 32; off > 0; off >>= 1) ldv += __shfl_down(ldv, off);
            if (r == 0) {
                stats[2*m]   += quad_add;
                stats[2*m+1] += ldv;
            }
        }
    }
    __syncthreads();

    if (!have) return;
    float* rowp = C + roff + p;
    #pragma unroll
    for (int j = 0; j < NB; ++j) {
        float s0 = l[j], s1 = 0.f, s2 = 0.f, s3 = 0.f;
        int c = 0;
        #pragma unroll
        for (; c + 4 <= j; c += 4) {
            float4 t = *(const float4*)&Tl[j][c];
            s0 = fmaf(-l[c],   t.x, s0);
            s1 = fmaf(-l[c+1], t.y, s1);
            s2 = fmaf(-l[c+2], t.z, s2);
            s3 = fmaf(-l[c+3], t.w, s3);
        }
        #pragma unroll
        for (; c < j; ++c) s0 = fmaf(-l[c], Tl[j][c], s0);
        l[j] = ((s0 + s1) + (s2 + s3)) * rs_s[j];
    }
    #pragma unroll
    for (int q = 0; q < NB/4; ++q) {
        float4 v; v.x = l[4*q]; v.y = l[4*q+1]; v.z = l[4*q+2]; v.w = l[4*q+3];
        *(float4*)(rowp + 4*q) = v;
    }
    float b0 = 0.f, b1 = 0.f, b2 = 0.f, b3 = 0.f;
    #pragma unroll
    for (int j = 0; j < NB; j += 4) {
        b0 = fmaf(l[j],   sol_s[j],   b0);
        b1 = fmaf(l[j+1], sol_s[j+1], b1);
        b2 = fmaf(l[j+2], sol_s[j+2], b2);
        b3 = fmaf(l[j+3], sol_s[j+3], b3);
    }
    bvec[(size_t)m * NN + r0] -= ((b0 + b1) + (b2 + b3));
}

// ---------------- tail SYRK, split-K partials -> psq ----------------
__global__ __launch_bounds__(256)
void tailsyrk_kernel(const float* __restrict__ covb, float* __restrict__ psq)
{
    int ml = blockIdx.y;
    const float* C = covb + (size_t)ml * SMPL;
    float* P = psq + (size_t)ml * PSQN;
    int z  = blockIdx.x;
    int k0 = z * (CROSS / 4);            // 224 per segment

    __shared__ __align__(16) float As[32][132];
    int tid = threadIdx.x;
    int tx = tid & 15, ty = tid >> 4;
    int c0 = tx * 8, r0 = ty * 8;

    float4 acc[8][2];
    #pragma unroll
    for (int r = 0; r < 8; ++r) { acc[r][0] = make_float4(0,0,0,0); acc[r][1] = make_float4(0,0,0,0); }

    for (int ks = k0; ks < k0 + CROSS/4; ks += 32) {
        for (int idx = tid; idx < 128 * 8; idx += 256) {
            int ii = idx >> 3;
            int c4 = (idx & 7) << 2;
            float4 v = *(const float4*)(C + rowoff(CROSS + ii) + ks + c4);
            As[c4+0][ii] = v.x; As[c4+1][ii] = v.y;
            As[c4+2][ii] = v.z; As[c4+3][ii] = v.w;
        }
        __syncthreads();
        #pragma unroll
        for (int k = 0; k < 32; ++k) {
            float4 b0 = *(const float4*)&As[k][c0];
            float4 b1 = *(const float4*)&As[k][c0 + 4];
            float4 a0 = *(const float4*)&As[k][r0];
            float4 a1 = *(const float4*)&As[k][r0 + 4];
            float ar[8] = {a0.x, a0.y, a0.z, a0.w, a1.x, a1.y, a1.z, a1.w};
            #pragma unroll
            for (int r = 0; r < 8; ++r) {
                fma4(acc[r][0], ar[r], b0);
                fma4(acc[r][1], ar[r], b1);
            }
        }
        __syncthreads();
    }

    #pragma unroll
    for (int r = 0; r < 8; ++r) {
        float* cp = P + (r0 + r) * 512 + z * 128 + c0;
        *(float4*)cp = acc[r][0];
        *((float4*)cp + 1) = acc[r][1];
    }
}

// ---------------- fused tailreduce + per-sample finish ----------------
__global__ __launch_bounds__(512)
void finish_kernel(const float* __restrict__ tsq, const float* __restrict__ psq,
                   const float* __restrict__ bvec,
                   const float* __restrict__ stats, float* __restrict__ out,
                   const float* __restrict__ scal, int mbase)
{
    int ml = blockIdx.x;
    int m  = mbase + ml;
    const float* T = tsq + (size_t)ml * TSQN;
    const float* P = psq + (size_t)ml * PSQN;
    __shared__ __align__(16) float A11[NB][68];   // tail 11; after TRSM: k-major L21 (Ps)
    __shared__ __align__(16) float A21[NB][68];   // tail rows 64..127, cols 0..63
    __shared__ __align__(16) float A22[NB][68];
    __shared__ float rs_s[NB], sol_s[NB];
    __shared__ float bt[TB];
    __shared__ float s_quad, s_ld;
    int tid = threadIdx.x;

    if (tid < TB) bt[tid] = bvec[(size_t)m * NN + CROSS + tid];
    if (tid == 0) { s_quad = 0.f; s_ld = 0.f; }

    // ---- fused tail reduce: A = tsq - sum_z psq partials ----
    float4 tv[6], p0[6], p1[6], p2[6], p3[6];
    const float* pbase[6];
    #pragma unroll
    for (int u = 0; u < 6; ++u) {
        int f   = tid + u * 512;
        int i   = (f & 1023) >> 4;
        int c4  = (f & 15) << 2;
        int blk = f >> 10;
        int ti  = (blk == 0) ? i : (64 + i);         // tail-local row
        int tc  = (blk == 2) ? (64 + c4) : c4;       // tail-local col
        pbase[u] = P + ti * 512 + tc;
        tv[u] = *(const float4*)(T + ti * TB + tc);
    }
    #pragma unroll
    for (int u = 0; u < 6; ++u) p0[u] = *(const float4*)(pbase[u]);
    #pragma unroll
    for (int u = 0; u < 6; ++u) p1[u] = *(const float4*)(pbase[u] + 128);
    #pragma unroll
    for (int u = 0; u < 6; ++u) p2[u] = *(const float4*)(pbase[u] + 256);
    #pragma unroll
    for (int u = 0; u < 6; ++u) p3[u] = *(const float4*)(pbase[u] + 384);
    #pragma unroll
    for (int u = 0; u < 6; ++u) {
        int f   = tid + u * 512;
        int i   = (f & 1023) >> 4;
        int c4  = (f & 15) << 2;
        int blk = f >> 10;
        float4 s;
        s.x = ((p0[u].x + p1[u].x) + p2[u].x) + p3[u].x;
        s.y = ((p0[u].y + p1[u].y) + p2[u].y) + p3[u].y;
        s.z = ((p0[u].z + p1[u].z) + p2[u].z) + p3[u].z;
        s.w = ((p0[u].w + p1[u].w) + p2[u].w) + p3[u].w;
        float4 t = tv[u];
        t.x -= s.x; t.y -= s.y; t.z -= s.z; t.w -= s.w;
        float* dst = (blk == 0) ? &A11[i][c4] : ((blk == 1) ? &A21[i][c4] : &A22[i][c4]);
        *(float4*)dst = t;
    }
    __syncthreads();

    // ---- factor A11 (64x64), scaled rows back into A11 ----
    if (tid < 64) {
        int r = tid;
        float row[NB];
        #pragma unroll
        for (int q = 0; q < NB/4; ++q) {
            float4 v = *(const float4*)&A11[r][4*q];
            row[4*q+0] = v.x; row[4*q+1] = v.y; row[4*q+2] = v.z; row[4*q+3] = v.w;
        }
        float b = bt[r];
        float quad_add = 0.f, my_d = 1.f;
        #pragma unroll
        for (int j = 0; j < NB; ++j) {
            float dj = fmaxf(bcastf(row[j], j), 1e-30f);
            float rs = rsqrtf(dj);
            if (r == j) my_d = dj;
            row[j] *= rs;
            float sj = bcastf(b, j) * rs;
            quad_add = fmaf(sj, sj, quad_add);
            b = fmaf(-row[j], sj, b);
            if (r == j) { rs_s[j] = rs; sol_s[j] = sj; }
            #pragma unroll
            for (int c = j + 1; c < NB; ++c) {
                float s = bcastf(row[j], c);
                row[c] = fmaf(-row[j], s, row[c]);
            }
        }
        #pragma unroll
        for (int q = 0; q < NB/4; ++q) {
            float4 v; v.x = row[4*q]; v.y = row[4*q+1]; v.z = row[4*q+2]; v.w = row[4*q+3];
            *(float4*)&A11[r][4*q] = v;
        }
        float ldv = logf(my_d);
        #pragma unroll
        for (int off = 32; off > 0; off >>= 1) ldv += __shfl_down(ldv, off);
        if (r == 0) { s_quad += quad_add; s_ld += ldv; }
    }
    __syncthreads();

    // ---- TRSM: rows of A21 (wave 1); result transposed into A11 (k-major Ps) ----
    if (tid >= 64 && tid < 128) {
        int rr = tid - 64;
        float l[NB];
        #pragma unroll
        for (int q = 0; q < NB/4; ++q) {
            float4 v = *(const float4*)&A21[rr][4*q];
            l[4*q] = v.x; l[4*q+1] = v.y; l[4*q+2] = v.z; l[4*q+3] = v.w;
        }
        #pragma unroll
        for (int j = 0; j < NB; ++j) {
            float s0 = l[j], s1 = 0.f, s2 = 0.f, s3 = 0.f;
            int c = 0;
            #pragma unroll
            for (; c + 4 <= j; c += 4) {
                float4 t = *(const float4*)&A11[j][c];
                s0 = fmaf(-l[c],   t.x, s0);
                s1 = fmaf(-l[c+1], t.y, s1);
                s2 = fmaf(-l[c+2], t.z, s2);
                s3 = fmaf(-l[c+3], t.w, s3);
            }
            #pragma unroll
            for (; c < j; ++c) s0 = fmaf(-l[c], A11[j][c], s0);
            l[j] = ((s0 + s1) + (s2 + s3)) * rs_s[j];
        }
        // A11 is dead now; single-wave program order makes this race-free.
        #pragma unroll
        for (int k = 0; k < NB; ++k) A11[k][rr] = l[k];   // Ps[k][rr]
        float bacc = 0.f;
        #pragma unroll
        for (int j = 0; j < NB; ++j) bacc = fmaf(l[j], sol_s[j], bacc);
        bt[64 + rr] -= bacc;
    }
    __syncthreads();

    // ---- SYRK: A22 -= L21 * L21^T, k-major Ps (= A11), conflict-free ----
    for (int idx = tid; idx < 64 * 16; idx += 512) {
        int i  = idx >> 4;
        int j4 = (idx & 15) << 2;
        if (j4 > i) continue;
        float4 a = make_float4(0,0,0,0);
        #pragma unroll 8
        for (int k = 0; k < NB; ++k) {
            float4 pj = *(const float4*)&A11[k][j4];
            fma4(a, A11[k][i], pj);
        }
        float* cp = &A22[i][j4];
        float4 uu = *(float4*)cp;
        uu.x -= a.x; uu.y -= a.y; uu.z -= a.z; uu.w -= a.w;
        *(float4*)cp = uu;
    }
    __syncthreads();

    // ---- factor A22 (64x64); only logdet + quad needed ----
    if (tid < 64) {
        int r = tid;
        float row[NB];
        #pragma unroll
        for (int q = 0; q < NB/4; ++q) {
            float4 v = *(const float4*)&A22[r][4*q];
            row[4*q+0] = v.x; row[4*q+1] = v.y; row[4*q+2] = v.z; row[4*q+3] = v.w;
        }
        float b = bt[64 + r];
        float quad_add = 0.f, my_d = 1.f;
        #pragma unroll
        for (int j = 0; j < NB; ++j) {
            float dj = fmaxf(bcastf(row[j], j), 1e-30f);
            float rs = rsqrtf(dj);
            if (r == j) my_d = dj;
            row[j] *= rs;
            float sj = bcastf(b, j) * rs;
            quad_add = fmaf(sj, sj, quad_add);
            b = fmaf(-row[j], sj, b);
            #pragma unroll
            for (int c = j + 1; c < NB; ++c) {
                float s = bcastf(row[j], c);
                row[c] = fmaf(-row[j], s, row[c]);
            }
        }
        float ldv = logf(my_d);
        #pragma unroll
        for (int off = 32; off > 0; off >>= 1) ldv += __shfl_down(ldv, off);
        if (r == 0) { s_quad += quad_add; s_ld += ldv; }
    }
    __syncthreads();

    if (tid == 0) {
        float qt = stats[2*m]   + s_quad;
        float lt = stats[2*m+1] + s_ld;
        out[m] = -0.5f * (qt + lt + (float)NN * LOG2PI) + scal[5*NSAMP + m];
    }
}

extern "C" void kernel_launch(void* const* d_in, const int* in_sizes, int n_in,
                              void* d_out, int out_size, void* d_ws, size_t ws_size,
                              hipStream_t stream)
{
    const float* x   = (const float*)d_in[0];
    const float* y   = (const float*)d_in[1];
    const float* z   = (const float*)d_in[2];
    const float* qbm = (const float*)d_in[3];
    const float* qbs = (const float*)d_in[4];
    const float* qsm = (const float*)d_in[5];
    const float* qss = (const float*)d_in[6];
    const float* qem = (const float*)d_in[7];
    const float* qes = (const float*)d_in[8];
    const float* qzm = (const float*)d_in[9];
    const float* qzs = (const float*)d_in[10];
    const float* qnm = (const float*)d_in[11];
    const float* qns = (const float*)d_in[12];
    float* out  = (float*)d_out;
    float* ws   = (float*)d_ws;

    // workspace layout (floats)
    float* scal   = ws;                                   // 384 used
    float* bvec   = ws + 1024;                            // 64*1024
    float* stats  = ws + 1024 + NSAMP*NN;                 // 128 used, 512 res
    float* tsq    = ws + 1024 + NSAMP*NN + 512;           // 64 * 128*128 (4MB)
    float* psq    = tsq + (size_t)NSAMP * TSQN;           // 64 * 128*512 (16MB)
    float* cov    = psq + (size_t)NSAMP * PSQN;           // 64 * SMPL (147MB banded)
    size_t headF  = 1024 + (size_t)NSAMP*NN + 512;

    scal_kernel<<<1, 64, 0, stream>>>(z, qbm, qbs, qsm, qss, qem, qes, qzm, qzs, qnm, qns, scal);

    size_t availF = ws_size / 4;
    size_t perM   = (size_t)SMPL + TSQN + PSQN;   // per-sample footprint
    int mc_max = NSAMP;
    if (availF < headF + (size_t)NSAMP * perM) {
        size_t rem = (availF > headF) ? (availF - headF) : 0;
        mc_max = (int)(rem / perM);
        if (mc_max < 1) mc_max = 1;
        if (mc_max > NSAMP) mc_max = NSAMP;
    }

    for (int mb = 0; mb < NSAMP; mb += mc_max) {
        int mc = NSAMP - mb; if (mc > mc_max) mc = mc_max;
        covslim_kernel<<<dim3(80, mc), 256, 0, stream>>>(cov, tsq, scal, x, y, bvec, stats, mb);
        for (int q = 0; q < CROSS / NB; ++q) {   // panels p = 0..832
            int p = q * NB;
            if (q > 0) {
                int rows = NN - p;
                int rt128 = (rows + 127) / 128;
                if (rt128 * mc >= 448) {
                    update_kernel<<<dim3(rt128 * mc), 256, 0, stream>>>(cov, scal, x, mb, p, mc);
                } else {
                    int rt64 = (rows + 63) / 64;
                    update_small_kernel<<<dim3(rt64 * mc * 2), 256, 0, stream>>>(cov, scal, x, mb, p, mc, rt64);
                }
            }
            int rb = NN - p - NB;
            int rtiles = (rb + 127) / 128;
            trsm_kernel<<<dim3(rtiles * mc), 128, 0, stream>>>(cov, bvec, stats, mb, p, mc);
        }
        tailsyrk_kernel<<<dim3(4, mc), 256, 0, stream>>>(cov, psq);
        finish_kernel<<<mc, 512, 0, stream>>>(tsq, psq, bvec, stats, out, scal, mb);
    }
}

// Round 18
// 1153.972 us; speedup vs baseline: 2.0429x; 1.0062x over previous
//
#include <hip/hip_runtime.h>
#include <math.h>

#define NN 1024           // N (logical)
#define NB 64             // panel width
#define TB 128            // tail handled by tailsyrk+finish
#define CROSS (NN - TB)   // 896: panel loop covers p < CROSS
#define NSAMP 64          // n_mc
// r25: banded-packed cov (147MB, one L3-resident batch). r26: pipelined
// staging. r29: tail pipeline XCD-aligned — covslim and tailsyrk grids
// flattened to ml-fastest 1D (ml = bid % mc), so sample ml's tsq tile and
// psq partials are written on XCD ml%8, where finish's block ml reads them
// (finish's 8.9MB at 120 GB/s was mostly cross-XCD).
#define SMPL 573440
#define TSQN (TB*TB)      // dense tail square per sample (finish input)
#define PSQN (TB*512)     // tailsyrk split-K partials per sample

#define CCONST  (-0.91893853320467274f)   // -0.5*log(2*pi)
#define LOG2PI  (1.8378770664093453f)

__device__ __forceinline__ int rowoff(int i) {
    int b = i >> 6;
    return (2048*b + 3072)*b + (i & 63)*(64*b + 80);
}
__device__ __forceinline__ float bcastf(float v, int lane) {
    return __int_as_float(__builtin_amdgcn_readlane(__float_as_int(v), lane));
}
__device__ __forceinline__ float softplus_d(float v) {
    return (v > 20.f ? v : log1pf(expf(v))) + 1e-7f;
}
__device__ __forceinline__ float log_normal_f(float v, float mean, float s, float eps) {
    float d = v - mean;
    return -d * d / (2.f * s * s + eps) - logf(s) + CCONST;
}
__device__ __forceinline__ float log_lognormal_f(float v, float mean, float s) {
    float lv = logf(v);
    float d = lv - mean;
    return -d * d / (2.f * s * s + 1e-6f) - lv - logf(s) + CCONST;
}
__device__ __forceinline__ void fma4(float4& c, float a, const float4& b) {
    c.x = fmaf(a, b.x, c.x); c.y = fmaf(a, b.y, c.y);
    c.z = fmaf(a, b.z, c.z); c.w = fmaf(a, b.w, c.w);
}

// ---------------- per-sample scalars ----------------
__global__ void scal_kernel(const float* __restrict__ z,
    const float* qbm, const float* qbs, const float* qsm, const float* qss,
    const float* qem, const float* qes, const float* qzm, const float* qzs,
    const float* qnm, const float* qns, float* __restrict__ scal)
{
    int m = threadIdx.x;
    if (m >= NSAMP) return;
    float z0 = z[m*5+0], z1 = z[m*5+1], z2 = z[m*5+2], z3 = z[m*5+3], z4 = z[m*5+4];
    float spb = softplus_d(qbs[0]);
    float sps = softplus_d(qss[0]);
    float spe = softplus_d(qes[0]);
    float spz = softplus_d(qzs[0]);
    float spn = softplus_d(qns[0]);
    float sigma2 = expf(z0 * sps + qsm[0]);
    float beta   = z1 * spb + qbm[0];
    float eta    = expf(z2 * spe + qem[0]);
    float lsZ    = expf(z3 * spz + qzm[0]);
    float lsN    = expf(z4 * spn + qnm[0]);
    float s0 = softplus_d(sqrtf(logf(2.f)));
    float lp = log_normal_f(beta, 0.f, 1.f, 1e-5f)
             + log_lognormal_f(sigma2, 1.f, s0)
             + log_lognormal_f(eta,    1.f, s0)
             + log_lognormal_f(lsZ,    1.f, s0)
             + log_lognormal_f(lsN,    1.f, s0);
    float lq = log_normal_f(beta, qbm[0], spb, 1e-5f)
             + log_lognormal_f(sigma2, qsm[0], sps)
             + log_lognormal_f(eta,    qem[0], spe)
             + log_lognormal_f(lsZ,    qzm[0], spz)
             + log_lognormal_f(lsN,    qnm[0], spn);
    scal[m]           = sigma2;
    scal[NSAMP + m]   = eta;
    scal[2*NSAMP + m] = 1.f / lsZ;
    scal[3*NSAMP + m] = 1.f / lsN;
    scal[4*NSAMP + m] = beta;
    scal[5*NSAMP + m] = lp - lq;
}

// ---------------- slim covariance build + bvec/stats init ----------------
// r29: 1D ml-fastest grid (tsq/stripe writes land on sample-local XCD L2).
__global__ __launch_bounds__(256)
void covslim_kernel(float* __restrict__ cov, float* __restrict__ tsq,
                    const float* __restrict__ scal,
                    const float* __restrict__ x, const float* __restrict__ y,
                    float* __restrict__ bvec, float* __restrict__ stats,
                    int mbase, int mc)
{
    int bid = blockIdx.x;
    int ml  = bid % mc;
    int bx  = bid / mc;                        // 0..79
    int m  = mbase + ml;
    float sigma2 = scal[m];
    float eta    = scal[NSAMP + m];
    float ilZ    = scal[2*NSAMP + m];
    float ilN    = scal[3*NSAMP + m];
    float* C = cov + (size_t)ml * SMPL;
    int tid = threadIdx.x;

    if (bx == 0 && tid == 0) { stats[2*m] = 0.f; stats[2*m+1] = 0.f; }

    if (bx < 64) {
        // stripe: 16 rows x 64 cols per block (lower triangle only)
        int i  = bx * 16 + (tid >> 4);
        int j0 = (tid & 15) * 4;
        if ((tid & 15) == 0) bvec[(size_t)m * NN + i] = y[i] - scal[4*NSAMP + m];
        if (j0 > i) return;
        float xi0 = x[2*i]   * ilZ;
        float xi1 = x[2*i+1] * ilN;
        float4 xa = *(const float4*)(x + 2*j0);
        float4 xb = *(const float4*)(x + 2*j0 + 4);
        float v[4]; float d0, d1;
        d0 = xa.x*ilZ - xi0; d1 = xa.y*ilN - xi1; v[0] = eta*__expf(-0.5f*(d0*d0+d1*d1));
        d0 = xa.z*ilZ - xi0; d1 = xa.w*ilN - xi1; v[1] = eta*__expf(-0.5f*(d0*d0+d1*d1));
        d0 = xb.x*ilZ - xi0; d1 = xb.y*ilN - xi1; v[2] = eta*__expf(-0.5f*(d0*d0+d1*d1));
        d0 = xb.z*ilZ - xi0; d1 = xb.w*ilN - xi1; v[3] = eta*__expf(-0.5f*(d0*d0+d1*d1));
        #pragma unroll
        for (int q = 0; q < 4; ++q) if (j0 + q == i) v[q] += sigma2;
        float* row = C + rowoff(i);
        if (j0 + 3 <= i) {
            float4 o; o.x = v[0]; o.y = v[1]; o.z = v[2]; o.w = v[3];
            *(float4*)(row + j0) = o;
        } else {
            #pragma unroll
            for (int q = 0; q < 4; ++q) if (j0 + q <= i) row[j0+q] = v[q];
        }
    } else {
        // tail: 8 rows x 128 cols per block -> dense tsq[128][128]
        int bx2 = bx - 64;                         // 0..15
        int tr  = bx2 * 8 + (tid >> 5);            // 0..127 tail-local row
        int tc  = (tid & 31) * 4;                  // 0..124 tail-local col
        int i   = CROSS + tr;
        int j0  = CROSS + tc;
        float xi0 = x[2*i]   * ilZ;
        float xi1 = x[2*i+1] * ilN;
        float4 xa = *(const float4*)(x + 2*j0);
        float4 xb = *(const float4*)(x + 2*j0 + 4);
        float v[4]; float d0, d1;
        d0 = xa.x*ilZ - xi0; d1 = xa.y*ilN - xi1; v[0] = eta*__expf(-0.5f*(d0*d0+d1*d1));
        d0 = xa.z*ilZ - xi0; d1 = xa.w*ilN - xi1; v[1] = eta*__expf(-0.5f*(d0*d0+d1*d1));
        d0 = xb.x*ilZ - xi0; d1 = xb.y*ilN - xi1; v[2] = eta*__expf(-0.5f*(d0*d0+d1*d1));
        d0 = xb.z*ilZ - xi0; d1 = xb.w*ilN - xi1; v[3] = eta*__expf(-0.5f*(d0*d0+d1*d1));
        #pragma unroll
        for (int q = 0; q < 4; ++q) if (j0 + q == i) v[q] += sigma2;
        float4 o; o.x = v[0]; o.y = v[1]; o.z = v[2]; o.w = v[3];
        *(float4*)(tsq + (size_t)ml * TSQN + tr * TB + tc) = o;
    }
}

// ---------------- left-looking block-column update (GEMM, K = p) ----------------
// r26: software-pipelined staging (works now that the set is L3-resident).
__global__ __launch_bounds__(256)
void update_kernel(float* __restrict__ covb, const float* __restrict__ scal,
                   const float* __restrict__ x, int mbase, int p, int mc)
{
    int bid = blockIdx.x;
    int ml  = bid % mc;
    int bx  = bid / mc;
    int m  = mbase + ml;
    float* C = covb + (size_t)ml * SMPL;
    int rowbase = p + bx * 128;
    int bofp = rowoff(p);
    int bsp  = 64*(p>>6) + 80;

    __shared__ __align__(16) float As[32][132];  // k-major, 128 rows
    __shared__ __align__(16) float Bs[32][68];   // k-major, 64 rows

    int tid = threadIdx.x;
    int tx = tid & 7,  ty = tid >> 3;
    int c0 = tx * 8,   r0 = ty * 4;

    float4 acc[4][2];
    #pragma unroll
    for (int r = 0; r < 4; ++r) { acc[r][0] = make_float4(0,0,0,0); acc[r][1] = make_float4(0,0,0,0); }

    // prefetch k-step 0 into registers
    float4 ra[4], rb[2];
    #pragma unroll
    for (int t = 0; t < 4; ++t) {
        int idx = tid + t * 256;
        int ii = idx >> 3, c4 = (idx & 7) << 2;
        int gr = rowbase + ii;
        ra[t] = make_float4(0,0,0,0);
        if (gr < NN) ra[t] = *(const float4*)(C + rowoff(gr) + c4);
    }
    #pragma unroll
    for (int t = 0; t < 2; ++t) {
        int idx = tid + t * 256;
        int ii = idx >> 3, c4 = (idx & 7) << 2;
        rb[t] = *(const float4*)(C + bofp + ii * bsp + c4);
    }

    for (int ks = 0; ks < p; ks += 32) {
        #pragma unroll
        for (int t = 0; t < 4; ++t) {
            int idx = tid + t * 256;
            int ii = idx >> 3, c4 = (idx & 7) << 2;
            As[c4+0][ii] = ra[t].x; As[c4+1][ii] = ra[t].y;
            As[c4+2][ii] = ra[t].z; As[c4+3][ii] = ra[t].w;
        }
        #pragma unroll
        for (int t = 0; t < 2; ++t) {
            int idx = tid + t * 256;
            int ii = idx >> 3, c4 = (idx & 7) << 2;
            Bs[c4+0][ii] = rb[t].x; Bs[c4+1][ii] = rb[t].y;
            Bs[c4+2][ii] = rb[t].z; Bs[c4+3][ii] = rb[t].w;
        }
        __syncthreads();
        int kn = ks + 32;
        if (kn < p) {
            #pragma unroll
            for (int t = 0; t < 4; ++t) {
                int idx = tid + t * 256;
                int ii = idx >> 3, c4 = (idx & 7) << 2;
                int gr = rowbase + ii;
                ra[t] = make_float4(0,0,0,0);
                if (gr < NN) ra[t] = *(const float4*)(C + rowoff(gr) + kn + c4);
            }
            #pragma unroll
            for (int t = 0; t < 2; ++t) {
                int idx = tid + t * 256;
                int ii = idx >> 3, c4 = (idx & 7) << 2;
                rb[t] = *(const float4*)(C + bofp + ii * bsp + kn + c4);
            }
        }
        #pragma unroll
        for (int k = 0; k < 32; ++k) {
            float4 b0 = *(const float4*)&Bs[k][c0];
            float4 b1 = *(const float4*)&Bs[k][c0 + 4];
            float4 a0 = *(const float4*)&As[k][r0];
            float ar[4] = {a0.x, a0.y, a0.z, a0.w};
            #pragma unroll
            for (int r = 0; r < 4; ++r) {
                fma4(acc[r][0], ar[r], b0);
                fma4(acc[r][1], ar[r], b1);
            }
        }
        __syncthreads();
    }

    int jcol = p + c0;
    float sigma2 = scal[m];
    float eta    = scal[NSAMP + m];
    float ilZ    = scal[2*NSAMP + m];
    float ilN    = scal[3*NSAMP + m];
    float4 xa0 = *(const float4*)(x + 2*jcol);
    float4 xb0 = *(const float4*)(x + 2*jcol + 4);
    float4 xa1 = *(const float4*)(x + 2*jcol + 8);
    float4 xb1 = *(const float4*)(x + 2*jcol + 12);
    #pragma unroll
    for (int r = 0; r < 4; ++r) {
        int g = rowbase + r0 + r;
        if (g < NN) {
            float xi0 = x[2*g]   * ilZ;
            float xi1 = x[2*g+1] * ilN;
            float v[8]; float d0, d1;
            d0 = xa0.x*ilZ - xi0; d1 = xa0.y*ilN - xi1; v[0] = eta*__expf(-0.5f*(d0*d0+d1*d1));
            d0 = xa0.z*ilZ - xi0; d1 = xa0.w*ilN - xi1; v[1] = eta*__expf(-0.5f*(d0*d0+d1*d1));
            d0 = xb0.x*ilZ - xi0; d1 = xb0.y*ilN - xi1; v[2] = eta*__expf(-0.5f*(d0*d0+d1*d1));
            d0 = xb0.z*ilZ - xi0; d1 = xb0.w*ilN - xi1; v[3] = eta*__expf(-0.5f*(d0*d0+d1*d1));
            d0 = xa1.x*ilZ - xi0; d1 = xa1.y*ilN - xi1; v[4] = eta*__expf(-0.5f*(d0*d0+d1*d1));
            d0 = xa1.z*ilZ - xi0; d1 = xa1.w*ilN - xi1; v[5] = eta*__expf(-0.5f*(d0*d0+d1*d1));
            d0 = xb1.x*ilZ - xi0; d1 = xb1.y*ilN - xi1; v[6] = eta*__expf(-0.5f*(d0*d0+d1*d1));
            d0 = xb1.z*ilZ - xi0; d1 = xb1.w*ilN - xi1; v[7] = eta*__expf(-0.5f*(d0*d0+d1*d1));
            #pragma unroll
            for (int qq = 0; qq < 8; ++qq) if (jcol + qq == g) v[qq] += sigma2;
            float* cp = C + rowoff(g) + jcol;
            float4 u0, u1;
            u0.x = v[0] - acc[r][0].x; u0.y = v[1] - acc[r][0].y;
            u0.z = v[2] - acc[r][0].z; u0.w = v[3] - acc[r][0].w;
            u1.x = v[4] - acc[r][1].x; u1.y = v[5] - acc[r][1].y;
            u1.z = v[6] - acc[r][1].z; u1.w = v[7] - acc[r][1].w;
            *(float4*)cp = u0;
            *((float4*)cp + 1) = u1;
        }
    }
}

// ---------------- small-tile update for late panels ----------------
__global__ __launch_bounds__(256)
void update_small_kernel(float* __restrict__ covb, const float* __restrict__ scal,
                         const float* __restrict__ x, int mbase, int p, int mc, int nbx)
{
    int bid  = blockIdx.x;
    int ml   = bid % mc;
    int rest = bid / mc;
    int bx   = rest % nbx;
    int zz   = rest / nbx;
    int m  = mbase + ml;
    float* C = covb + (size_t)ml * SMPL;
    int rowbase = p + bx * 64;
    int zoff = zz * 32;
    int bofp = rowoff(p);
    int bsp  = 64*(p>>6) + 80;

    __shared__ __align__(16) float As[32][68];   // k-major, 64 rows
    __shared__ __align__(16) float Bs[32][36];   // k-major, 32 rows

    int tid = threadIdx.x;
    int tx = tid & 7,  ty = tid >> 3;   // 8 col-quads x 32 row-pairs
    int c0 = tx * 4,   r0 = ty * 2;

    float4 acc0 = make_float4(0,0,0,0), acc1 = make_float4(0,0,0,0);

    float4 ra[2], rb1;
    #pragma unroll
    for (int t = 0; t < 2; ++t) {
        int idx = tid + t * 256;
        int ii = idx >> 3, c4 = (idx & 7) << 2;
        int gr = rowbase + ii;
        ra[t] = make_float4(0,0,0,0);
        if (gr < NN) ra[t] = *(const float4*)(C + rowoff(gr) + c4);
    }
    {
        int ii = tid >> 3, c4 = (tid & 7) << 2;
        rb1 = *(const float4*)(C + bofp + (zoff + ii) * bsp + c4);
    }

    for (int ks = 0; ks < p; ks += 32) {
        #pragma unroll
        for (int t = 0; t < 2; ++t) {
            int idx = tid + t * 256;
            int ii = idx >> 3, c4 = (idx & 7) << 2;
            As[c4+0][ii] = ra[t].x; As[c4+1][ii] = ra[t].y;
            As[c4+2][ii] = ra[t].z; As[c4+3][ii] = ra[t].w;
        }
        {
            int ii = tid >> 3, c4 = (tid & 7) << 2;
            Bs[c4+0][ii] = rb1.x; Bs[c4+1][ii] = rb1.y;
            Bs[c4+2][ii] = rb1.z; Bs[c4+3][ii] = rb1.w;
        }
        __syncthreads();
        int kn = ks + 32;
        if (kn < p) {
            #pragma unroll
            for (int t = 0; t < 2; ++t) {
                int idx = tid + t * 256;
                int ii = idx >> 3, c4 = (idx & 7) << 2;
                int gr = rowbase + ii;
                ra[t] = make_float4(0,0,0,0);
                if (gr < NN) ra[t] = *(const float4*)(C + rowoff(gr) + kn + c4);
            }
            {
                int ii = tid >> 3, c4 = (tid & 7) << 2;
                rb1 = *(const float4*)(C + bofp + (zoff + ii) * bsp + kn + c4);
            }
        }
        #pragma unroll
        for (int k = 0; k < 32; ++k) {
            float4 bv = *(const float4*)&Bs[k][c0];
            float2 av = *(const float2*)&As[k][r0];
            fma4(acc0, av.x, bv);
            fma4(acc1, av.y, bv);
        }
        __syncthreads();
    }

    int jcol = p + zoff + c0;
    float sigma2 = scal[m];
    float eta    = scal[NSAMP + m];
    float ilZ    = scal[2*NSAMP + m];
    float ilN    = scal[3*NSAMP + m];
    float4 xa = *(const float4*)(x + 2*jcol);
    float4 xb = *(const float4*)(x + 2*jcol + 4);
    int g0 = rowbase + r0;
    #pragma unroll
    for (int rr = 0; rr < 2; ++rr) {
        int g = g0 + rr;
        if (g < NN) {
            float xi0 = x[2*g]   * ilZ;
            float xi1 = x[2*g+1] * ilN;
            float v[4]; float d0, d1;
            d0 = xa.x*ilZ - xi0; d1 = xa.y*ilN - xi1; v[0] = eta*__expf(-0.5f*(d0*d0+d1*d1));
            d0 = xa.z*ilZ - xi0; d1 = xa.w*ilN - xi1; v[1] = eta*__expf(-0.5f*(d0*d0+d1*d1));
            d0 = xb.x*ilZ - xi0; d1 = xb.y*ilN - xi1; v[2] = eta*__expf(-0.5f*(d0*d0+d1*d1));
            d0 = xb.z*ilZ - xi0; d1 = xb.w*ilN - xi1; v[3] = eta*__expf(-0.5f*(d0*d0+d1*d1));
            #pragma unroll
            for (int qq = 0; qq < 4; ++qq) if (jcol + qq == g) v[qq] += sigma2;
            const float4 ac = (rr == 0) ? acc0 : acc1;
            float* cp = C + rowoff(g) + jcol;
            float4 u;
            u.x = v[0] - ac.x; u.y = v[1] - ac.y; u.z = v[2] - ac.z; u.w = v[3] - ac.w;
            *(float4*)cp = u;
        }
    }
}

// ---------------- fused diag-factor + panel TRSM ----------------
__global__ __launch_bounds__(128)
void trsm_kernel(float* __restrict__ covb, float* __restrict__ bvec,
                 float* __restrict__ stats, int mbase, int p, int mc)
{
    int bid = blockIdx.x;
    int ml  = bid % mc;
    int bx  = bid / mc;
    int m  = mbase + ml;
    float* C = covb + (size_t)ml * SMPL;
    __shared__ __align__(16) float Tl[NB][68];
    __shared__ float rs_s[NB], sol_s[NB];
    int tid = threadIdx.x;
    int bofp = rowoff(p);
    int bsp  = 64*(p>>6) + 80;

    // preload solve rows (global loads in flight while wave 0 factors)
    int r0 = p + NB + bx * 128 + tid;
    bool have = (r0 < NN);
    float l[NB];
    int roff = have ? rowoff(r0) : 0;
    if (have) {
        const float* rowp = C + roff + p;
        #pragma unroll
        for (int q = 0; q < NB/4; ++q) {
            float4 v = *(const float4*)(rowp + 4*q);
            l[4*q] = v.x; l[4*q+1] = v.y; l[4*q+2] = v.z; l[4*q+3] = v.w;
        }
    }

    // ---- in-block diag factor (wave 0), verbatim diag arithmetic
    if (tid < 64) {
        int r = tid;
        float row[NB];
        const float* src = C + bofp + r * bsp + p;
        #pragma unroll
        for (int q = 0; q < NB/4; ++q) {
            float4 v = *(const float4*)(src + 4*q);
            row[4*q+0] = v.x; row[4*q+1] = v.y; row[4*q+2] = v.z; row[4*q+3] = v.w;
        }
        float b = bvec[(size_t)m * NN + p + r];
        float quad_add = 0.f, my_d = 1.f, my_rs = 0.f, my_sol = 0.f;
        #pragma unroll
        for (int j = 0; j < NB; ++j) {
            float dj = fmaxf(bcastf(row[j], j), 1e-30f);
            float rs = rsqrtf(dj);
            if (r == j) my_d = dj;
            row[j] *= rs;                       // row[j] = L[r][j] for r>=j
            float sj = bcastf(b, j) * rs;
            quad_add = fmaf(sj, sj, quad_add);
            b = fmaf(-row[j], sj, b);
            if (r == j) { my_rs = rs; my_sol = sj; }
            #pragma unroll
            for (int c = j + 1; c < NB; ++c) {
                float s = bcastf(row[j], c);    // = L[c][j]
                row[c] = fmaf(-row[j], s, row[c]);
            }
        }
        #pragma unroll
        for (int q = 0; q < NB/4; ++q) {
            float4 v; v.x = row[4*q]; v.y = row[4*q+1]; v.z = row[4*q+2]; v.w = row[4*q+3];
            *(float4*)&Tl[r][4*q] = v;
        }
        rs_s[r]  = my_rs;
        sol_s[r] = my_sol;
        if (bx == 0) {
            float ldv = logf(my_d);
            #pragma unroll
            for (int off = 32; off > 0; off >>= 1) ldv += __shfl_down(ldv, off);
            if (r == 0) {
                stats[2*m]   += quad_add;
                stats[2*m+1] += ldv;
            }
        }
    }
    __syncthreads();

    if (!have) return;
    float* rowp = C + roff + p;
    #pragma unroll
    for (int j = 0; j < NB; ++j) {
        float s0 = l[j], s1 = 0.f, s2 = 0.f, s3 = 0.f;
        int c = 0;
        #pragma unroll
        for (; c + 4 <= j; c += 4) {
            float4 t = *(const float4*)&Tl[j][c];
            s0 = fmaf(-l[c],   t.x, s0);
            s1 = fmaf(-l[c+1], t.y, s1);
            s2 = fmaf(-l[c+2], t.z, s2);
            s3 = fmaf(-l[c+3], t.w, s3);
        }
        #pragma unroll
        for (; c < j; ++c) s0 = fmaf(-l[c], Tl[j][c], s0);
        l[j] = ((s0 + s1) + (s2 + s3)) * rs_s[j];
    }
    #pragma unroll
    for (int q = 0; q < NB/4; ++q) {
        float4 v; v.x = l[4*q]; v.y = l[4*q+1]; v.z = l[4*q+2]; v.w = l[4*q+3];
        *(float4*)(rowp + 4*q) = v;
    }
    float b0 = 0.f, b1 = 0.f, b2 = 0.f, b3 = 0.f;
    #pragma unroll
    for (int j = 0; j < NB; j += 4) {
        b0 = fmaf(l[j],   sol_s[j],   b0);
        b1 = fmaf(l[j+1], sol_s[j+1], b1);
        b2 = fmaf(l[j+2], sol_s[j+2], b2);
        b3 = fmaf(l[j+3], sol_s[j+3], b3);
    }
    bvec[(size_t)m * NN + r0] -= ((b0 + b1) + (b2 + b3));
}

// ---------------- tail SYRK, split-K partials -> psq ----------------
// r29: 1D ml-fastest grid (ml = bid % mc, z = bid / mc) so sample ml's
// partials are written on XCD ml%8, where finish's block ml reads them.
__global__ __launch_bounds__(256)
void tailsyrk_kernel(const float* __restrict__ covb, float* __restrict__ psq, int mc)
{
    int bid = blockIdx.x;
    int ml  = bid % mc;
    int z   = bid / mc;
    const float* C = covb + (size_t)ml * SMPL;
    float* P = psq + (size_t)ml * PSQN;
    int k0 = z * (CROSS / 4);            // 224 per segment

    __shared__ __align__(16) float As[32][132];
    int tid = threadIdx.x;
    int tx = tid & 15, ty = tid >> 4;
    int c0 = tx * 8, r0 = ty * 8;

    float4 acc[8][2];
    #pragma unroll
    for (int r = 0; r < 8; ++r) { acc[r][0] = make_float4(0,0,0,0); acc[r][1] = make_float4(0,0,0,0); }

    for (int ks = k0; ks < k0 + CROSS/4; ks += 32) {
        for (int idx = tid; idx < 128 * 8; idx += 256) {
            int ii = idx >> 3;
            int c4 = (idx & 7) << 2;
            float4 v = *(const float4*)(C + rowoff(CROSS + ii) + ks + c4);
            As[c4+0][ii] = v.x; As[c4+1][ii] = v.y;
            As[c4+2][ii] = v.z; As[c4+3][ii] = v.w;
        }
        __syncthreads();
        #pragma unroll
        for (int k = 0; k < 32; ++k) {
            float4 b0 = *(const float4*)&As[k][c0];
            float4 b1 = *(const float4*)&As[k][c0 + 4];
            float4 a0 = *(const float4*)&As[k][r0];
            float4 a1 = *(const float4*)&As[k][r0 + 4];
            float ar[8] = {a0.x, a0.y, a0.z, a0.w, a1.x, a1.y, a1.z, a1.w};
            #pragma unroll
            for (int r = 0; r < 8; ++r) {
                fma4(acc[r][0], ar[r], b0);
                fma4(acc[r][1], ar[r], b1);
            }
        }
        __syncthreads();
    }

    #pragma unroll
    for (int r = 0; r < 8; ++r) {
        float* cp = P + (r0 + r) * 512 + z * 128 + c0;
        *(float4*)cp = acc[r][0];
        *((float4*)cp + 1) = acc[r][1];
    }
}

// ---------------- fused tailreduce + per-sample finish ----------------
__global__ __launch_bounds__(512)
void finish_kernel(const float* __restrict__ tsq, const float* __restrict__ psq,
                   const float* __restrict__ bvec,
                   const float* __restrict__ stats, float* __restrict__ out,
                   const float* __restrict__ scal, int mbase)
{
    int ml = blockIdx.x;
    int m  = mbase + ml;
    const float* T = tsq + (size_t)ml * TSQN;
    const float* P = psq + (size_t)ml * PSQN;
    __shared__ __align__(16) float A11[NB][68];   // tail 11; after TRSM: k-major L21 (Ps)
    __shared__ __align__(16) float A21[NB][68];   // tail rows 64..127, cols 0..63
    __shared__ __align__(16) float A22[NB][68];
    __shared__ float rs_s[NB], sol_s[NB];
    __shared__ float bt[TB];
    __shared__ float s_quad, s_ld;
    int tid = threadIdx.x;

    if (tid < TB) bt[tid] = bvec[(size_t)m * NN + CROSS + tid];
    if (tid == 0) { s_quad = 0.f; s_ld = 0.f; }

    // ---- fused tail reduce: A = tsq - sum_z psq partials ----
    float4 tv[6], p0[6], p1[6], p2[6], p3[6];
    const float* pbase[6];
    #pragma unroll
    for (int u = 0; u < 6; ++u) {
        int f   = tid + u * 512;
        int i   = (f & 1023) >> 4;
        int c4  = (f & 15) << 2;
        int blk = f >> 10;
        int ti  = (blk == 0) ? i : (64 + i);         // tail-local row
        int tc  = (blk == 2) ? (64 + c4) : c4;       // tail-local col
        pbase[u] = P + ti * 512 + tc;
        tv[u] = *(const float4*)(T + ti * TB + tc);
    }
    #pragma unroll
    for (int u = 0; u < 6; ++u) p0[u] = *(const float4*)(pbase[u]);
    #pragma unroll
    for (int u = 0; u < 6; ++u) p1[u] = *(const float4*)(pbase[u] + 128);
    #pragma unroll
    for (int u = 0; u < 6; ++u) p2[u] = *(const float4*)(pbase[u] + 256);
    #pragma unroll
    for (int u = 0; u < 6; ++u) p3[u] = *(const float4*)(pbase[u] + 384);
    #pragma unroll
    for (int u = 0; u < 6; ++u) {
        int f   = tid + u * 512;
        int i   = (f & 1023) >> 4;
        int c4  = (f & 15) << 2;
        int blk = f >> 10;
        float4 s;
        s.x = ((p0[u].x + p1[u].x) + p2[u].x) + p3[u].x;
        s.y = ((p0[u].y + p1[u].y) + p2[u].y) + p3[u].y;
        s.z = ((p0[u].z + p1[u].z) + p2[u].z) + p3[u].z;
        s.w = ((p0[u].w + p1[u].w) + p2[u].w) + p3[u].w;
        float4 t = tv[u];
        t.x -= s.x; t.y -= s.y; t.z -= s.z; t.w -= s.w;
        float* dst = (blk == 0) ? &A11[i][c4] : ((blk == 1) ? &A21[i][c4] : &A22[i][c4]);
        *(float4*)dst = t;
    }
    __syncthreads();

    // ---- factor A11 (64x64), scaled rows back into A11 ----
    if (tid < 64) {
        int r = tid;
        float row[NB];
        #pragma unroll
        for (int q = 0; q < NB/4; ++q) {
            float4 v = *(const float4*)&A11[r][4*q];
            row[4*q+0] = v.x; row[4*q+1] = v.y; row[4*q+2] = v.z; row[4*q+3] = v.w;
        }
        float b = bt[r];
        float quad_add = 0.f, my_d = 1.f;
        #pragma unroll
        for (int j = 0; j < NB; ++j) {
            float dj = fmaxf(bcastf(row[j], j), 1e-30f);
            float rs = rsqrtf(dj);
            if (r == j) my_d = dj;
            row[j] *= rs;
            float sj = bcastf(b, j) * rs;
            quad_add = fmaf(sj, sj, quad_add);
            b = fmaf(-row[j], sj, b);
            if (r == j) { rs_s[j] = rs; sol_s[j] = sj; }
            #pragma unroll
            for (int c = j + 1; c < NB; ++c) {
                float s = bcastf(row[j], c);
                row[c] = fmaf(-row[j], s, row[c]);
            }
        }
        #pragma unroll
        for (int q = 0; q < NB/4; ++q) {
            float4 v; v.x = row[4*q]; v.y = row[4*q+1]; v.z = row[4*q+2]; v.w = row[4*q+3];
            *(float4*)&A11[r][4*q] = v;
        }
        float ldv = logf(my_d);
        #pragma unroll
        for (int off = 32; off > 0; off >>= 1) ldv += __shfl_down(ldv, off);
        if (r == 0) { s_quad += quad_add; s_ld += ldv; }
    }
    __syncthreads();

    // ---- TRSM: rows of A21 (wave 1); result transposed into A11 (k-major Ps) ----
    if (tid >= 64 && tid < 128) {
        int rr = tid - 64;
        float l[NB];
        #pragma unroll
        for (int q = 0; q < NB/4; ++q) {
            float4 v = *(const float4*)&A21[rr][4*q];
            l[4*q] = v.x; l[4*q+1] = v.y; l[4*q+2] = v.z; l[4*q+3] = v.w;
        }
        #pragma unroll
        for (int j = 0; j < NB; ++j) {
            float s0 = l[j], s1 = 0.f, s2 = 0.f, s3 = 0.f;
            int c = 0;
            #pragma unroll
            for (; c + 4 <= j; c += 4) {
                float4 t = *(const float4*)&A11[j][c];
                s0 = fmaf(-l[c],   t.x, s0);
                s1 = fmaf(-l[c+1], t.y, s1);
                s2 = fmaf(-l[c+2], t.z, s2);
                s3 = fmaf(-l[c+3], t.w, s3);
            }
            #pragma unroll
            for (; c < j; ++c) s0 = fmaf(-l[c], A11[j][c], s0);
            l[j] = ((s0 + s1) + (s2 + s3)) * rs_s[j];
        }
        // A11 is dead now; single-wave program order makes this race-free.
        #pragma unroll
        for (int k = 0; k < NB; ++k) A11[k][rr] = l[k];   // Ps[k][rr]
        float bacc = 0.f;
        #pragma unroll
        for (int j = 0; j < NB; ++j) bacc = fmaf(l[j], sol_s[j], bacc);
        bt[64 + rr] -= bacc;
    }
    __syncthreads();

    // ---- SYRK: A22 -= L21 * L21^T, k-major Ps (= A11), conflict-free ----
    for (int idx = tid; idx < 64 * 16; idx += 512) {
        int i  = idx >> 4;
        int j4 = (idx & 15) << 2;
        if (j4 > i) continue;
        float4 a = make_float4(0,0,0,0);
        #pragma unroll 8
        for (int k = 0; k < NB; ++k) {
            float4 pj = *(const float4*)&A11[k][j4];
            fma4(a, A11[k][i], pj);
        }
        float* cp = &A22[i][j4];
        float4 uu = *(float4*)cp;
        uu.x -= a.x; uu.y -= a.y; uu.z -= a.z; uu.w -= a.w;
        *(float4*)cp = uu;
    }
    __syncthreads();

    // ---- factor A22 (64x64); only logdet + quad needed ----
    if (tid < 64) {
        int r = tid;
        float row[NB];
        #pragma unroll
        for (int q = 0; q < NB/4; ++q) {
            float4 v = *(const float4*)&A22[r][4*q];
            row[4*q+0] = v.x; row[4*q+1] = v.y; row[4*q+2] = v.z; row[4*q+3] = v.w;
        }
        float b = bt[64 + r];
        float quad_add = 0.f, my_d = 1.f;
        #pragma unroll
        for (int j = 0; j < NB; ++j) {
            float dj = fmaxf(bcastf(row[j], j), 1e-30f);
            float rs = rsqrtf(dj);
            if (r == j) my_d = dj;
            row[j] *= rs;
            float sj = bcastf(b, j) * rs;
            quad_add = fmaf(sj, sj, quad_add);
            b = fmaf(-row[j], sj, b);
            #pragma unroll
            for (int c = j + 1; c < NB; ++c) {
                float s = bcastf(row[j], c);
                row[c] = fmaf(-row[j], s, row[c]);
            }
        }
        float ldv = logf(my_d);
        #pragma unroll
        for (int off = 32; off > 0; off >>= 1) ldv += __shfl_down(ldv, off);
        if (r == 0) { s_quad += quad_add; s_ld += ldv; }
    }
    __syncthreads();

    if (tid == 0) {
        float qt = stats[2*m]   + s_quad;
        float lt = stats[2*m+1] + s_ld;
        out[m] = -0.5f * (qt + lt + (float)NN * LOG2PI) + scal[5*NSAMP + m];
    }
}

extern "C" void kernel_launch(void* const* d_in, const int* in_sizes, int n_in,
                              void* d_out, int out_size, void* d_ws, size_t ws_size,
                              hipStream_t stream)
{
    const float* x   = (const float*)d_in[0];
    const float* y   = (const float*)d_in[1];
    const float* z   = (const float*)d_in[2];
    const float* qbm = (const float*)d_in[3];
    const float* qbs = (const float*)d_in[4];
    const float* qsm = (const float*)d_in[5];
    const float* qss = (const float*)d_in[6];
    const float* qem = (const float*)d_in[7];
    const float* qes = (const float*)d_in[8];
    const float* qzm = (const float*)d_in[9];
    const float* qzs = (const float*)d_in[10];
    const float* qnm = (const float*)d_in[11];
    const float* qns = (const float*)d_in[12];
    float* out  = (float*)d_out;
    float* ws   = (float*)d_ws;

    // workspace layout (floats)
    float* scal   = ws;                                   // 384 used
    float* bvec   = ws + 1024;                            // 64*1024
    float* stats  = ws + 1024 + NSAMP*NN;                 // 128 used, 512 res
    float* tsq    = ws + 1024 + NSAMP*NN + 512;           // 64 * 128*128 (4MB)
    float* psq    = tsq + (size_t)NSAMP * TSQN;           // 64 * 128*512 (16MB)
    float* cov    = psq + (size_t)NSAMP * PSQN;           // 64 * SMPL (147MB banded)
    size_t headF  = 1024 + (size_t)NSAMP*NN + 512;

    scal_kernel<<<1, 64, 0, stream>>>(z, qbm, qbs, qsm, qss, qem, qes, qzm, qzs, qnm, qns, scal);

    size_t availF = ws_size / 4;
    size_t perM   = (size_t)SMPL + TSQN + PSQN;   // per-sample footprint
    int mc_max = NSAMP;
    if (availF < headF + (size_t)NSAMP * perM) {
        size_t rem = (availF > headF) ? (availF - headF) : 0;
        mc_max = (int)(rem / perM);
        if (mc_max < 1) mc_max = 1;
        if (mc_max > NSAMP) mc_max = NSAMP;
    }

    for (int mb = 0; mb < NSAMP; mb += mc_max) {
        int mc = NSAMP - mb; if (mc > mc_max) mc = mc_max;
        covslim_kernel<<<dim3(80 * mc), 256, 0, stream>>>(cov, tsq, scal, x, y, bvec, stats, mb, mc);
        for (int q = 0; q < CROSS / NB; ++q) {   // panels p = 0..832
            int p = q * NB;
            if (q > 0) {
                int rows = NN - p;
                int rt128 = (rows + 127) / 128;
                if (rt128 * mc >= 448) {
                    update_kernel<<<dim3(rt128 * mc), 256, 0, stream>>>(cov, scal, x, mb, p, mc);
                } else {
                    int rt64 = (rows + 63) / 64;
                    update_small_kernel<<<dim3(rt64 * mc * 2), 256, 0, stream>>>(cov, scal, x, mb, p, mc, rt64);
                }
            }
            int rb = NN - p - NB;
            int rtiles = (rb + 127) / 128;
            trsm_kernel<<<dim3(rtiles * mc), 128, 0, stream>>>(cov, bvec, stats, mb, p, mc);
        }
        tailsyrk_kernel<<<dim3(4 * mc), 256, 0, stream>>>(cov, psq, mc);
        finish_kernel<<<mc, 512, 0, stream>>>(tsq, psq, bvec, stats, out, scal, mb);
    }
}